// Round 1
// baseline (306.933 us; speedup 1.0000x reference)
//
#include <hip/hip_runtime.h>
#include <hip/hip_bf16.h>
#include <cstdint>
#include <cstddef>

// Problem constants
#define NT 8192
#define DD 512
#define HH 2048
#define NE 4
// ffn tiles: BM=256, BK=32, 4-slot LDS ring, counted-vmcnt pipeline
#define SLOT1 16384    // ffn1 slot shorts: A 256x32 (8192) + B 256x32 (8192)
#define SLOT2 12288    // ffn2 slot shorts: A 256x32 (8192) + B 128x32 (4096)
#define RP1 264        // ffn1 repack row stride (shorts), 16B-aligned, 4-bank row shift
#define RP2C 136       // ffn2 repack row stride (shorts), 16B-aligned
#define FFN1_GRID 576  // 9 mt-groups x 8 xcd x 8 n-tiles (covers <=67 m-tiles of 256)
#define FFN2_GRID 288  // 9 mt-groups x 8 xcd x 4 n-tiles

typedef short short8 __attribute__((ext_vector_type(8)));
typedef float floatx4 __attribute__((ext_vector_type(4)));

static __device__ __forceinline__ unsigned short f2bf(float f) {
    union { float f; uint32_t u; } v; v.f = f;
    uint32_t u = v.u;
    u += 0x7FFFu + ((u >> 16) & 1u);   // round-to-nearest-even
    return (unsigned short)(u >> 16);
}
static __device__ __forceinline__ float bf2f(unsigned short u) {
    union { uint32_t u; float f; } v; v.u = ((uint32_t)u) << 16; return v.f;
}

// async global->LDS, 16B per lane. LDS dest = wave-uniform base + lane*16 (addresses below are lane-linear).
static __device__ __forceinline__ void gld_lds16(const unsigned short* g, unsigned short* l) {
    __builtin_amdgcn_global_load_lds(
        (const __attribute__((address_space(1))) void*)g,
        (__attribute__((address_space(3))) void*)l, 16, 0, 0);
}

// ------------- merged prep (512 thr): weight transpose+cast (blocks 0..4095) + gate (4096..) -------------
__global__ __launch_bounds__(512) void k_prep(
    const float* __restrict__ w1, unsigned short* __restrict__ w1t,
    const float* __restrict__ w2, unsigned short* __restrict__ w2t,
    const float* __restrict__ h, const float* __restrict__ wg,
    int* __restrict__ sel, float* __restrict__ gv, unsigned short* __restrict__ hb) {
    int t = threadIdx.x;
    if (blockIdx.x < 4096) {
        int z = blockIdx.x >> 9;            // 512 blocks per expert-matrix
        int rem = blockIdx.x & 511;
        const float* in; unsigned short* out; int R, C, by, bx;
        if (z < 4) {
            in = w1 + (size_t)z * DD * HH; out = w1t + (size_t)z * DD * HH;
            R = DD; C = HH; by = rem >> 6; bx = rem & 63;      // 8 x 64
        } else {
            in = w2 + (size_t)(z - 4) * HH * DD; out = w2t + (size_t)(z - 4) * HH * DD;
            R = HH; C = DD; by = rem >> 4; bx = rem & 15;      // 32 x 16
        }
        int r0 = by * 64, c0 = bx * 32;
        __shared__ float tile[64][33];
        int tx = t & 31, ty = t >> 5;       // 32 x 16
#pragma unroll
        for (int it = 0; it < 4; it++) {
            int r = ty + it * 16;
            tile[r][tx] = in[(size_t)(r0 + r) * C + c0 + tx];
        }
        __syncthreads();
        int c8 = t >> 6, tx64 = t & 63;     // 8 out-cols per pass x 64-wide rows
#pragma unroll
        for (int it = 0; it < 4; it++) {
            int c = c8 + it * 8;
            out[(size_t)(c0 + c) * R + r0 + tx64] = f2bf(tile[tx64][c]);
        }
        return;
    }
    // ---- gating: fp32 logits, exact top-2, softmax over top-2, fused h->bf16 cast (8 tokens/block) ----
    int wid = t >> 6, lane = t & 63;
    int n = (blockIdx.x - 4096) * 8 + wid;
    const float* hr = h + (size_t)n * DD;
    int d0 = lane * 8;
    float hv[8];
    *(float4*)(hv)     = *(const float4*)(hr + d0);
    *(float4*)(hv + 4) = *(const float4*)(hr + d0 + 4);
    unsigned short tmp[8];
#pragma unroll
    for (int j = 0; j < 8; j++) tmp[j] = f2bf(hv[j]);
    *(uint4*)(hb + (size_t)n * DD + d0) = *(const uint4*)tmp;

    float a0 = 0.f, a1 = 0.f, a2 = 0.f, a3 = 0.f;
#pragma unroll
    for (int j = 0; j < 8; j++) {
        float4 w = *(const float4*)(wg + (size_t)(d0 + j) * 4);
        a0 += hv[j] * w.x; a1 += hv[j] * w.y; a2 += hv[j] * w.z; a3 += hv[j] * w.w;
    }
#pragma unroll
    for (int off = 32; off; off >>= 1) {
        a0 += __shfl_xor(a0, off);
        a1 += __shfl_xor(a1, off);
        a2 += __shfl_xor(a2, off);
        a3 += __shfl_xor(a3, off);
    }
    if (lane == 0) {
        float v[4] = {a0, a1, a2, a3};
        int e0 = 0; float b = v[0];
#pragma unroll
        for (int e = 1; e < 4; e++) if (v[e] > b) { b = v[e]; e0 = e; }
        int e1 = -1; float b2 = -1e30f;
#pragma unroll
        for (int e = 0; e < 4; e++) if (e != e0 && v[e] > b2) { b2 = v[e]; e1 = e; }
        float x = expf(b2 - b);
        float s = 1.f + x;
        sel[2 * n] = e0; sel[2 * n + 1] = e1;
        gv[2 * n] = 1.f / s; gv[2 * n + 1] = x / s;
    }
}

// ---------------- single-block scan (1024 thr, wave-level shfl scans, 2 barriers) ----------------
// ctl: [8..11]=expert base, [12]=total, [13]=n256 tiles
__global__ __launch_bounds__(1024) void k_scan(const int* __restrict__ sel, const float* __restrict__ gv,
                                               int* __restrict__ ctl, int* __restrict__ rtok,
                                               float* __restrict__ rgte, int* __restrict__ slotof,
                                               int* __restrict__ tiles) {
    __shared__ int wtot[4][16];
    __shared__ int wbase[4][16];
    __shared__ int ebase[4];
    int t = threadIdx.x, w = t >> 6, lane = t & 63;
    int c[4] = {0, 0, 0, 0};
    int selloc[16];
    const int4* s4 = (const int4*)sel;
#pragma unroll
    for (int i = 0; i < 4; i++) {
        int4 v = s4[t * 4 + i];
        selloc[i * 4 + 0] = v.x; c[v.x]++;
        selloc[i * 4 + 1] = v.y; c[v.y]++;
        selloc[i * 4 + 2] = v.z; c[v.z]++;
        selloc[i * 4 + 3] = v.w; c[v.w]++;
    }
    int inc[4] = {c[0], c[1], c[2], c[3]};
#pragma unroll
    for (int off = 1; off < 64; off <<= 1) {
#pragma unroll
        for (int e = 0; e < 4; e++) {
            int v = __shfl_up(inc[e], off);
            if (lane >= off) inc[e] += v;
        }
    }
    if (lane == 63)
#pragma unroll
        for (int e = 0; e < 4; e++) wtot[e][w] = inc[e];
    __syncthreads();
    if (t == 0) {
        int o = 0, nt = 0;
#pragma unroll
        for (int e = 0; e < 4; e++) {
            int s = 0;
            for (int ww = 0; ww < 16; ww++) { wbase[e][ww] = s; s += wtot[e][ww]; }
            ebase[e] = o; ctl[8 + e] = o;
            for (int m0 = 0; m0 < s; m0 += 256) tiles[nt++] = (e << 16) | m0;
            o += s;
        }
        ctl[12] = o; ctl[13] = nt;
    }
    __syncthreads();
    int pos[4];
#pragma unroll
    for (int e = 0; e < 4; e++) pos[e] = ebase[e] + wbase[e][w] + inc[e] - c[e];  // exclusive
#pragma unroll
    for (int i = 0; i < 16; i++) {
        int idx = t * 16 + i;          // = 2*n + k
        int e = selloc[i];
        int s = pos[e]++;
        rtok[s] = idx >> 1;
        rgte[s] = gv[idx];
        slotof[idx] = s;
    }
}

// ---- grouped GEMM 1: 256x256 tile, BK=32, 4-slot ring, 1 barrier + counted vmcnt per K-tile ----
// mid = relu(gather(h) @ w1[e] + b1[e]); 8 waves of 128x64; 4 gld_lds/thread/tile -> waits 8/4/0
__global__ __launch_bounds__(512, 2) void k_ffn1(
    const unsigned short* __restrict__ hb, const unsigned short* __restrict__ w1t,
    const float* __restrict__ b1, const int* __restrict__ ctl, const int* __restrict__ tiles,
    const int* __restrict__ rtok, unsigned short* __restrict__ mid) {
    // flat -> (xcd c, m-tile, n-tile): 8 n-tiles of one m-tile share c (same XCD L2 holds A rows)
    int flat = blockIdx.x;
    int c8 = flat & 7, q = flat >> 3;
    int nt = q & 7, mt = (q >> 3) * 8 + c8;
    if (mt >= ctl[13]) return;
    int tv = tiles[mt];
    int e = tv >> 16, m0 = tv & 0xFFFF;
    int base = ctl[8 + e];
    int cnt = ctl[9 + e] - base;
    int n0 = nt * 256;

    __shared__ unsigned short sm[67584];   // 4 slots x 16384 | epilogue repack 256 x RP1
    __shared__ int toks[256];

    int t = threadIdx.x;
    if (t < 256) {
        int r = m0 + t; if (r >= cnt) r = cnt - 1;
        toks[t] = rtok[base + r];
    }
    __syncthreads();

    const unsigned short* wB = w1t + (size_t)e * HH * DD;
    // staging addresses: rounds r=0,1 cover 256 rows x 4 granules of 16B; src granule pre-rotated by row
    const unsigned short* gA[2]; const unsigned short* gB[2];
    int lofA[2], lofB[2];
#pragma unroll
    for (int r = 0; r < 2; r++) {
        int idx = r * 512 + t;
        int row = idx >> 2, gd = idx & 3;
        int cg = (gd - row) & 3;
        gA[r] = hb + (size_t)toks[row] * DD + cg * 8;
        lofA[r] = idx * 8;
        gB[r] = wB + (size_t)(n0 + row) * DD + cg * 8;
        lofB[r] = 8192 + idx * 8;
    }

    int w = t >> 6, lane = t & 63;
    int wm = (w >> 2) * 128, wn = (w & 3) * 64;   // wave tile 128x64 (2M x 4N)
    int lrow = lane & 15, quad = lane >> 4;

    floatx4 acc[8][4];
#pragma unroll
    for (int i = 0; i < 8; i++)
#pragma unroll
        for (int j = 0; j < 4; j++) acc[i][j] = (floatx4)0.f;

    // prologue: stage K-tiles 0,1,2 into slots 0,1,2
#pragma unroll
    for (int tt = 0; tt < 3; tt++) {
        unsigned short* sb = sm + tt * SLOT1;
        int k0 = tt * 32;
#pragma unroll
        for (int r = 0; r < 2; r++) {
            gld_lds16(gA[r] + k0, sb + lofA[r]);
            gld_lds16(gB[r] + k0, sb + lofB[r]);
        }
    }

    const int NK = DD / 32;   // 16
    for (int tt = 0; tt < NK; tt++) {
        // counted wait: tiles tt+1, tt+2 (8 loads) may stay in flight across the barrier
        if (tt + 2 < NK)      asm volatile("s_waitcnt vmcnt(8)" ::: "memory");
        else if (tt + 1 < NK) asm volatile("s_waitcnt vmcnt(4)" ::: "memory");
        else                  asm volatile("s_waitcnt vmcnt(0)" ::: "memory");
        __builtin_amdgcn_s_barrier();
        asm volatile("" ::: "memory");     // keep stage issues below the barrier
        if (tt + 3 < NK) {                 // stage into slot freed by tile tt-1
            unsigned short* sb = sm + ((tt + 3) & 3) * SLOT1;
            int k0 = (tt + 3) * 32;
#pragma unroll
            for (int r = 0; r < 2; r++) {
                gld_lds16(gA[r] + k0, sb + lofA[r]);
                gld_lds16(gB[r] + k0, sb + lofB[r]);
            }
        }
        const unsigned short* SA = sm + (tt & 3) * SLOT1;
        const unsigned short* SB = SA + 8192;
        short8 af[8], bf[4];
#pragma unroll
        for (int i = 0; i < 8; i++) {
            int row = wm + 16 * i + lrow;
            af[i] = *(const short8*)&SA[row * 32 + ((quad + row) & 3) * 8];
        }
#pragma unroll
        for (int j = 0; j < 4; j++) {
            int row = wn + 16 * j + lrow;
            bf[j] = *(const short8*)&SB[row * 32 + ((quad + row) & 3) * 8];
        }
        __builtin_amdgcn_s_setprio(1);
#pragma unroll
        for (int i = 0; i < 8; i++)
#pragma unroll
            for (int j = 0; j < 4; j++)
                acc[i][j] = __builtin_amdgcn_mfma_f32_16x16x32_bf16(af[i], bf[j], acc[i][j], 0, 0, 0);
        __builtin_amdgcn_s_setprio(0);
    }
    __syncthreads();   // all reads of slots done before repack aliases them

    // epilogue: bias + relu -> repack -> coalesced 128B stores
    float bias[4];
#pragma unroll
    for (int j = 0; j < 4; j++) bias[j] = b1[e * HH + n0 + wn + 16 * j + lrow];
#pragma unroll
    for (int j = 0; j < 4; j++) {
        int col = wn + 16 * j + lrow;
#pragma unroll
        for (int i = 0; i < 8; i++) {
#pragma unroll
            for (int r = 0; r < 4; r++) {
                int m = wm + 16 * i + quad * 4 + r;
                float v = acc[i][j][r] + bias[j];
                v = v > 0.f ? v : 0.f;
                sm[m * RP1 + col] = f2bf(v);
            }
        }
    }
    __syncthreads();
#pragma unroll
    for (int it = 0; it < 2; it++) {
        int row = it * 128 + (t >> 2), seg = t & 3;   // 256 rows x 4 segs of 128B
        if (m0 + row < cnt) {
            unsigned short* dst = mid + (size_t)(base + m0 + row) * HH + n0 + seg * 64;
            const unsigned short* src = sm + row * RP1 + seg * 64;
#pragma unroll
            for (int k = 0; k < 8; k++)
                *(uint4*)(dst + k * 8) = *(const uint4*)(src + k * 8);
        }
    }
}

// ---- grouped GEMM 2: 256x128 tile, BK=32, 4-slot ring: ybuf[slot] = gate*(mid@w2[e]+b2[e]) ----
// 8 waves of 64x64; 3 gld_lds/thread/tile -> waits 6/3/0
__global__ __launch_bounds__(512, 2) void k_ffn2(
    const unsigned short* __restrict__ mid, const unsigned short* __restrict__ w2t,
    const float* __restrict__ b2, const int* __restrict__ ctl, const int* __restrict__ tiles,
    const float* __restrict__ rgte, unsigned short* __restrict__ ybuf) {
    int flat = blockIdx.x;
    int c8 = flat & 7, q = flat >> 3;
    int nt = q & 3, mt = (q >> 2) * 8 + c8;
    if (mt >= ctl[13]) return;
    int tv = tiles[mt];
    int e = tv >> 16, m0 = tv & 0xFFFF;
    int base = ctl[8 + e];
    int cnt = ctl[9 + e] - base;
    int n0 = nt * 128;

    __shared__ unsigned short sm[49152];   // 4 slots x 12288 | epilogue repack 256 x RP2C
    __shared__ float gts[256];

    int t = threadIdx.x;
    if (t < 256) {
        int r = m0 + t; if (r >= cnt) r = cnt - 1;
        gts[t] = rgte[base + r];
    }
    __syncthreads();

    const unsigned short* wB = w2t + (size_t)e * DD * HH;
    const unsigned short* gA[2]; const unsigned short* gB1;
    int lofA[2], lofB1;
#pragma unroll
    for (int r = 0; r < 2; r++) {
        int idx = r * 512 + t;
        int row = idx >> 2, gd = idx & 3;
        int cg = (gd - row) & 3;
        int ra = m0 + row; if (ra >= cnt) ra = cnt - 1;
        gA[r] = mid + (size_t)(base + ra) * HH + cg * 8;
        lofA[r] = idx * 8;
    }
    {
        int row = t >> 2, gd = t & 3;
        int cg = (gd - row) & 3;
        gB1 = wB + (size_t)(n0 + row) * HH + cg * 8;
        lofB1 = 8192 + t * 8;
    }

    int w = t >> 6, lane = t & 63;
    int wm = (w >> 1) * 64, wn = (w & 1) * 64;   // wave tile 64x64 (4M x 2N)
    int lrow = lane & 15, quad = lane >> 4;

    floatx4 acc[4][4];
#pragma unroll
    for (int i = 0; i < 4; i++)
#pragma unroll
        for (int j = 0; j < 4; j++) acc[i][j] = (floatx4)0.f;

#pragma unroll
    for (int tt = 0; tt < 3; tt++) {
        unsigned short* sb = sm + tt * SLOT2;
        int k0 = tt * 32;
        gld_lds16(gA[0] + k0, sb + lofA[0]);
        gld_lds16(gA[1] + k0, sb + lofA[1]);
        gld_lds16(gB1 + k0, sb + lofB1);
    }

    const int NK = HH / 32;   // 64
    for (int tt = 0; tt < NK; tt++) {
        if (tt + 2 < NK)      asm volatile("s_waitcnt vmcnt(6)" ::: "memory");
        else if (tt + 1 < NK) asm volatile("s_waitcnt vmcnt(3)" ::: "memory");
        else                  asm volatile("s_waitcnt vmcnt(0)" ::: "memory");
        __builtin_amdgcn_s_barrier();
        asm volatile("" ::: "memory");
        if (tt + 3 < NK) {
            unsigned short* sb = sm + ((tt + 3) & 3) * SLOT2;
            int k0 = (tt + 3) * 32;
            gld_lds16(gA[0] + k0, sb + lofA[0]);
            gld_lds16(gA[1] + k0, sb + lofA[1]);
            gld_lds16(gB1 + k0, sb + lofB1);
        }
        const unsigned short* SA = sm + (tt & 3) * SLOT2;
        const unsigned short* SB = SA + 8192;
        short8 af[4], bf[4];
#pragma unroll
        for (int i = 0; i < 4; i++) {
            int row = wm + 16 * i + lrow;
            af[i] = *(const short8*)&SA[row * 32 + ((quad + row) & 3) * 8];
        }
#pragma unroll
        for (int j = 0; j < 4; j++) {
            int row = wn + 16 * j + lrow;
            bf[j] = *(const short8*)&SB[row * 32 + ((quad + row) & 3) * 8];
        }
        __builtin_amdgcn_s_setprio(1);
#pragma unroll
        for (int i = 0; i < 4; i++)
#pragma unroll
            for (int j = 0; j < 4; j++)
                acc[i][j] = __builtin_amdgcn_mfma_f32_16x16x32_bf16(af[i], bf[j], acc[i][j], 0, 0, 0);
        __builtin_amdgcn_s_setprio(0);
    }
    __syncthreads();

    // epilogue: bias + gate-scale -> repack -> coalesced stores
    float b2v[4];
#pragma unroll
    for (int j = 0; j < 4; j++) b2v[j] = b2[e * DD + n0 + wn + 16 * j + lrow];
#pragma unroll
    for (int j = 0; j < 4; j++) {
        int col = wn + 16 * j + lrow;
#pragma unroll
        for (int i = 0; i < 4; i++) {
#pragma unroll
            for (int r = 0; r < 4; r++) {
                int m = wm + 16 * i + quad * 4 + r;
                float v = (acc[i][j][r] + b2v[j]) * gts[m];
                sm[m * RP2C + col] = f2bf(v);
            }
        }
    }
    __syncthreads();
    {
        int row = t >> 1, half = t & 1;   // 256 rows x 2 segs of 128B
        if (m0 + row < cnt) {
            unsigned short* dst = ybuf + (size_t)(base + m0 + row) * DD + n0 + half * 64;
            const unsigned short* src = sm + row * RP2C + half * 64;
#pragma unroll
            for (int k = 0; k < 8; k++)
                *(uint4*)(dst + k * 8) = *(const uint4*)(src + k * 8);
        }
    }
}

// ---------------- combine (512 thr, 4 tokens/block): out[n] = ybuf[slot(n,0)] + ybuf[slot(n,1)] ----------------
__global__ __launch_bounds__(512) void k_combine(const unsigned short* __restrict__ ybuf,
                                                 const int* __restrict__ slotof,
                                                 float* __restrict__ out) {
    int n = blockIdx.x * 4 + (threadIdx.x >> 7);
    int c = (threadIdx.x & 127) * 4;
    int sA = slotof[2 * n], sB = slotof[2 * n + 1];
    ushort4 a = *(const ushort4*)(ybuf + (size_t)sA * DD + c);
    ushort4 b = *(const ushort4*)(ybuf + (size_t)sB * DD + c);
    float4 o;
    o.x = bf2f(a.x) + bf2f(b.x);
    o.y = bf2f(a.y) + bf2f(b.y);
    o.z = bf2f(a.z) + bf2f(b.z);
    o.w = bf2f(a.w) + bf2f(b.w);
    *(float4*)(out + (size_t)n * DD + c) = o;
}

extern "C" void kernel_launch(void* const* d_in, const int* in_sizes, int n_in,
                              void* d_out, int out_size, void* d_ws, size_t ws_size,
                              hipStream_t stream) {
    const float* h  = (const float*)d_in[0];
    const float* wg = (const float*)d_in[1];
    const float* w1 = (const float*)d_in[2];
    const float* b1 = (const float*)d_in[3];
    const float* w2 = (const float*)d_in[4];
    const float* b2 = (const float*)d_in[5];
    float* out = (float*)d_out;

    char* ws = (char*)d_ws;
    size_t off = 0;
    auto alloc = [&](size_t bytes) -> void* {
        void* p = ws + off;
        off += (bytes + 255) & ~(size_t)255;
        return p;
    };
    unsigned short* hb  = (unsigned short*)alloc((size_t)NT * DD * 2);        // dead after ffn1
    unsigned short* w1t = (unsigned short*)alloc((size_t)NE * HH * DD * 2);   // dead after ffn1
    unsigned short* w2t = (unsigned short*)alloc((size_t)NE * DD * HH * 2);
    int*   sel    = (int*)alloc((size_t)NT * 2 * 4);
    float* gv     = (float*)alloc((size_t)NT * 2 * 4);
    int*   ctl    = (int*)alloc(256);
    int*   tiles  = (int*)alloc(1024);
    int*   rtok   = (int*)alloc((size_t)NT * 2 * 4);
    float* rgte   = (float*)alloc((size_t)NT * 2 * 4);
    int*   slotof = (int*)alloc((size_t)NT * 2 * 4);
    unsigned short* mid = (unsigned short*)alloc((size_t)NT * 2 * HH * 2);
    // ybuf [NT*2][DD] bf16 (16.7 MB) aliases hb+w1t (16.7 MB), both dead before ffn2 runs
    unsigned short* ybuf = (unsigned short*)ws;

    k_prep<<<dim3(4096 + NT / 8), 512, 0, stream>>>(w1, w1t, w2, w2t, h, wg, sel, gv, hb);
    k_scan<<<1, 1024, 0, stream>>>(sel, gv, ctl, rtok, rgte, slotof, tiles);
    k_ffn1<<<dim3(FFN1_GRID), 512, 0, stream>>>(hb, w1t, b1, ctl, tiles, rtok, mid);
    k_ffn2<<<dim3(FFN2_GRID), 512, 0, stream>>>(mid, w2t, b2, ctl, tiles, rgte, ybuf);
    k_combine<<<dim3(NT / 4), 512, 0, stream>>>(ybuf, slotof, out);
}

// Round 2
// 280.659 us; speedup vs baseline: 1.0936x; 1.0936x over previous
//
#include <hip/hip_runtime.h>
#include <hip/hip_bf16.h>
#include <cstdint>
#include <cstddef>

// Problem constants
#define NT 8192
#define DD 512
#define HH 2048
#define NE 4
// ffn tiles: BK=64 (proven 0-conflict 8-granule swizzle), 2-slot dbuf, counted-vmcnt pipeline
#define SLOT1 32768    // ffn1 slot shorts: A 256x64 (16384) + B 256x64 (16384)
#define ASZ1  16384
#define SLOT2 24576    // ffn2 slot shorts: A 256x64 (16384) + B 128x64 (8192)
#define ASZ2  16384
#define RP1 264        // ffn1 repack row stride (shorts), 16B-aligned, +8 pad (proven class)
#define RP2 136        // ffn2 repack row stride (shorts)
#define FFN1_GRID 576  // 9 mt-groups x 8 xcd x 8 n-tiles (covers <=67 m-tiles of 256)
#define FFN2_GRID 288  // 9 mt-groups x 8 xcd x 4 n-tiles

typedef short short8 __attribute__((ext_vector_type(8)));
typedef float floatx4 __attribute__((ext_vector_type(4)));

static __device__ __forceinline__ unsigned short f2bf(float f) {
    union { float f; uint32_t u; } v; v.f = f;
    uint32_t u = v.u;
    u += 0x7FFFu + ((u >> 16) & 1u);   // round-to-nearest-even
    return (unsigned short)(u >> 16);
}
static __device__ __forceinline__ float bf2f(unsigned short u) {
    union { uint32_t u; float f; } v; v.u = ((uint32_t)u) << 16; return v.f;
}

// async global->LDS, 16B per lane. LDS dest = wave-uniform base + lane*16 (addresses below are lane-linear).
static __device__ __forceinline__ void gld_lds16(const unsigned short* g, unsigned short* l) {
    __builtin_amdgcn_global_load_lds(
        (const __attribute__((address_space(1))) void*)g,
        (__attribute__((address_space(3))) void*)l, 16, 0, 0);
}

// ------------- merged prep (512 thr): weight transpose+cast (blocks 0..4095) + gate (4096..) -------------
__global__ __launch_bounds__(512) void k_prep(
    const float* __restrict__ w1, unsigned short* __restrict__ w1t,
    const float* __restrict__ w2, unsigned short* __restrict__ w2t,
    const float* __restrict__ h, const float* __restrict__ wg,
    int* __restrict__ sel, float* __restrict__ gv, unsigned short* __restrict__ hb) {
    int t = threadIdx.x;
    if (blockIdx.x < 4096) {
        int z = blockIdx.x >> 9;            // 512 blocks per expert-matrix
        int rem = blockIdx.x & 511;
        const float* in; unsigned short* out; int R, C, by, bx;
        if (z < 4) {
            in = w1 + (size_t)z * DD * HH; out = w1t + (size_t)z * DD * HH;
            R = DD; C = HH; by = rem >> 6; bx = rem & 63;      // 8 x 64
        } else {
            in = w2 + (size_t)(z - 4) * HH * DD; out = w2t + (size_t)(z - 4) * HH * DD;
            R = HH; C = DD; by = rem >> 4; bx = rem & 15;      // 32 x 16
        }
        int r0 = by * 64, c0 = bx * 32;
        __shared__ float tile[64][33];
        int tx = t & 31, ty = t >> 5;       // 32 x 16
#pragma unroll
        for (int it = 0; it < 4; it++) {
            int r = ty + it * 16;
            tile[r][tx] = in[(size_t)(r0 + r) * C + c0 + tx];
        }
        __syncthreads();
        int c8 = t >> 6, tx64 = t & 63;     // 8 out-cols per pass x 64-wide rows
#pragma unroll
        for (int it = 0; it < 4; it++) {
            int c = c8 + it * 8;
            out[(size_t)(c0 + c) * R + r0 + tx64] = f2bf(tile[tx64][c]);
        }
        return;
    }
    // ---- gating: fp32 logits, exact top-2, softmax over top-2, fused h->bf16 cast (8 tokens/block) ----
    int wid = t >> 6, lane = t & 63;
    int n = (blockIdx.x - 4096) * 8 + wid;
    const float* hr = h + (size_t)n * DD;
    int d0 = lane * 8;
    float hv[8];
    *(float4*)(hv)     = *(const float4*)(hr + d0);
    *(float4*)(hv + 4) = *(const float4*)(hr + d0 + 4);
    unsigned short tmp[8];
#pragma unroll
    for (int j = 0; j < 8; j++) tmp[j] = f2bf(hv[j]);
    *(uint4*)(hb + (size_t)n * DD + d0) = *(const uint4*)tmp;

    float a0 = 0.f, a1 = 0.f, a2 = 0.f, a3 = 0.f;
#pragma unroll
    for (int j = 0; j < 8; j++) {
        float4 w = *(const float4*)(wg + (size_t)(d0 + j) * 4);
        a0 += hv[j] * w.x; a1 += hv[j] * w.y; a2 += hv[j] * w.z; a3 += hv[j] * w.w;
    }
#pragma unroll
    for (int off = 32; off; off >>= 1) {
        a0 += __shfl_xor(a0, off);
        a1 += __shfl_xor(a1, off);
        a2 += __shfl_xor(a2, off);
        a3 += __shfl_xor(a3, off);
    }
    if (lane == 0) {
        float v[4] = {a0, a1, a2, a3};
        int e0 = 0; float b = v[0];
#pragma unroll
        for (int e = 1; e < 4; e++) if (v[e] > b) { b = v[e]; e0 = e; }
        int e1 = -1; float b2 = -1e30f;
#pragma unroll
        for (int e = 0; e < 4; e++) if (e != e0 && v[e] > b2) { b2 = v[e]; e1 = e; }
        float x = expf(b2 - b);
        float s = 1.f + x;
        sel[2 * n] = e0; sel[2 * n + 1] = e1;
        gv[2 * n] = 1.f / s; gv[2 * n + 1] = x / s;
    }
}

// ---------------- single-block scan (1024 thr, wave-level shfl scans, 2 barriers) ----------------
// ctl: [8..11]=expert base, [12]=total, [13]=n256 tiles
__global__ __launch_bounds__(1024) void k_scan(const int* __restrict__ sel, const float* __restrict__ gv,
                                               int* __restrict__ ctl, int* __restrict__ rtok,
                                               float* __restrict__ rgte, int* __restrict__ slotof,
                                               int* __restrict__ tiles) {
    __shared__ int wtot[4][16];
    __shared__ int wbase[4][16];
    __shared__ int ebase[4];
    int t = threadIdx.x, w = t >> 6, lane = t & 63;
    int c[4] = {0, 0, 0, 0};
    int selloc[16];
    const int4* s4 = (const int4*)sel;
#pragma unroll
    for (int i = 0; i < 4; i++) {
        int4 v = s4[t * 4 + i];
        selloc[i * 4 + 0] = v.x; c[v.x]++;
        selloc[i * 4 + 1] = v.y; c[v.y]++;
        selloc[i * 4 + 2] = v.z; c[v.z]++;
        selloc[i * 4 + 3] = v.w; c[v.w]++;
    }
    int inc[4] = {c[0], c[1], c[2], c[3]};
#pragma unroll
    for (int off = 1; off < 64; off <<= 1) {
#pragma unroll
        for (int e = 0; e < 4; e++) {
            int v = __shfl_up(inc[e], off);
            if (lane >= off) inc[e] += v;
        }
    }
    if (lane == 63)
#pragma unroll
        for (int e = 0; e < 4; e++) wtot[e][w] = inc[e];
    __syncthreads();
    if (t == 0) {
        int o = 0, nt = 0;
#pragma unroll
        for (int e = 0; e < 4; e++) {
            int s = 0;
            for (int ww = 0; ww < 16; ww++) { wbase[e][ww] = s; s += wtot[e][ww]; }
            ebase[e] = o; ctl[8 + e] = o;
            for (int m0 = 0; m0 < s; m0 += 256) tiles[nt++] = (e << 16) | m0;
            o += s;
        }
        ctl[12] = o; ctl[13] = nt;
    }
    __syncthreads();
    int pos[4];
#pragma unroll
    for (int e = 0; e < 4; e++) pos[e] = ebase[e] + wbase[e][w] + inc[e] - c[e];  // exclusive
#pragma unroll
    for (int i = 0; i < 16; i++) {
        int idx = t * 16 + i;          // = 2*n + k
        int e = selloc[i];
        int s = pos[e]++;
        rtok[s] = idx >> 1;
        rgte[s] = gv[idx];
        slotof[idx] = s;
    }
}

// ---- grouped GEMM 1: 256x256 tile, BK=64, 2-slot dbuf, counted vmcnt (8 in flight across barriers) ----
// mid = relu(gather(h) @ w1[e] + b1[e]); 8 waves of 128x64 (2Mx4N); 8 gld_lds/thread/K-tile
__global__ __launch_bounds__(512, 2) void k_ffn1(
    const unsigned short* __restrict__ hb, const unsigned short* __restrict__ w1t,
    const float* __restrict__ b1, const int* __restrict__ ctl, const int* __restrict__ tiles,
    const int* __restrict__ rtok, unsigned short* __restrict__ mid) {
    // flat -> (xcd c8, m-tile, n-tile): 8 n-tiles of one m-tile share c8 (same XCD L2 holds A rows)
    int flat = blockIdx.x;
    int c8 = flat & 7, q = flat >> 3;
    int nt = q & 7, mt = (q >> 3) * 8 + c8;
    if (mt >= ctl[13]) return;
    int tv = tiles[mt];
    int e = tv >> 16, m0 = tv & 0xFFFF;
    int base = ctl[8 + e];
    int cnt = ctl[9 + e] - base;
    int n0 = nt * 256;

    __shared__ unsigned short sm[2 * SLOT1];   // 128 KB dbuf; epilogue repack aliases (128 x RP1 per half)
    __shared__ int toks[256];

    int t = threadIdx.x;
    if (t < 256) {
        int r = m0 + t; if (r >= cnt) r = cnt - 1;
        toks[t] = rtok[base + r];
    }
    __syncthreads();

    const unsigned short* wB = w1t + (size_t)e * HH * DD;
    // staging: 4 rounds cover 256 rows x 8 granules of 16B; src granule pre-rotated by row (proven layout)
    const unsigned short* gA[4]; const unsigned short* gB[4];
    int lof[4];
#pragma unroll
    for (int r = 0; r < 4; r++) {
        int idx = r * 512 + t;
        int row = idx >> 3, sch = idx & 7;
        int cg = (sch - row) & 7;
        gA[r] = hb + (size_t)toks[row] * DD + cg * 8;
        gB[r] = wB + (size_t)(n0 + row) * DD + cg * 8;
        lof[r] = idx * 8;                      // = row*64 + sch*8, lane-linear within a wave
    }

    int w = t >> 6, lane = t & 63;
    int wm = (w >> 2) * 128, wn = (w & 3) * 64;   // wave tile 128x64
    int lrow = lane & 15, quad = lane >> 4;

    floatx4 acc[8][4];
#pragma unroll
    for (int i = 0; i < 8; i++)
#pragma unroll
        for (int j = 0; j < 4; j++) acc[i][j] = (floatx4)0.f;

    // prologue: stage K-tile 0 into slot 0
#pragma unroll
    for (int r = 0; r < 4; r++) {
        gld_lds16(gA[r], sm + lof[r]);
        gld_lds16(gB[r], sm + ASZ1 + lof[r]);
    }

    const int NK = DD / 64;   // 8
    for (int tt = 0; tt < NK; tt++) {
        // issue next tile into the other slot (that slot was fully read in iter tt-1, barrier-protected),
        // then counted wait: only tile tt's 8 loads must land; tile tt+1's 8 stay in flight across the barrier.
        if (tt + 1 < NK) {
            unsigned short* sb = sm + ((tt + 1) & 1) * SLOT1;
            int k0 = (tt + 1) * 64;
#pragma unroll
            for (int r = 0; r < 4; r++) {
                gld_lds16(gA[r] + k0, sb + lof[r]);
                gld_lds16(gB[r] + k0, sb + ASZ1 + lof[r]);
            }
            asm volatile("s_waitcnt vmcnt(8)" ::: "memory");
        } else {
            asm volatile("s_waitcnt vmcnt(0)" ::: "memory");
        }
        __builtin_amdgcn_s_barrier();
        asm volatile("" ::: "memory");
        const unsigned short* SA = sm + (tt & 1) * SLOT1;
        const unsigned short* SB = SA + ASZ1;
#pragma unroll
        for (int ks = 0; ks < 2; ks++) {
            short8 af[8], bf[4];
#pragma unroll
            for (int i = 0; i < 8; i++) {
                int row = wm + 16 * i + lrow;
                af[i] = *(const short8*)&SA[row * 64 + (((ks << 2) + quad + row) & 7) * 8];
            }
#pragma unroll
            for (int j = 0; j < 4; j++) {
                int row = wn + 16 * j + lrow;
                bf[j] = *(const short8*)&SB[row * 64 + (((ks << 2) + quad + row) & 7) * 8];
            }
            __builtin_amdgcn_s_setprio(1);
#pragma unroll
            for (int i = 0; i < 8; i++)
#pragma unroll
                for (int j = 0; j < 4; j++)
                    acc[i][j] = __builtin_amdgcn_mfma_f32_16x16x32_bf16(af[i], bf[j], acc[i][j], 0, 0, 0);
            __builtin_amdgcn_s_setprio(0);
        }
        asm volatile("" ::: "memory");
        __builtin_amdgcn_s_barrier();
        asm volatile("" ::: "memory");
    }
    __syncthreads();   // full drain before repack aliases the slots

    // epilogue: bias + relu -> repack (two 128-row passes) -> coalesced 128B stores
    float bias[4];
#pragma unroll
    for (int j = 0; j < 4; j++) bias[j] = b1[e * HH + n0 + wn + 16 * j + lrow];
#pragma unroll
    for (int half = 0; half < 2; half++) {
        if ((w >> 2) == half) {
#pragma unroll
            for (int j = 0; j < 4; j++) {
                int col = wn + 16 * j + lrow;
#pragma unroll
                for (int i = 0; i < 8; i++) {
#pragma unroll
                    for (int r = 0; r < 4; r++) {
                        int lm = 16 * i + quad * 4 + r;    // local row within half
                        float v = acc[i][j][r] + bias[j];
                        v = v > 0.f ? v : 0.f;
                        sm[lm * RP1 + col] = f2bf(v);
                    }
                }
            }
        }
        __syncthreads();
        int row = t >> 2, seg = t & 3;    // 128 rows x 4 segs of 128B
        int grow = half * 128 + row;
        if (m0 + grow < cnt) {
            unsigned short* dst = mid + (size_t)(base + m0 + grow) * HH + n0 + seg * 64;
            const unsigned short* src = sm + row * RP1 + seg * 64;
#pragma unroll
            for (int k = 0; k < 8; k++)
                *(uint4*)(dst + k * 8) = *(const uint4*)(src + k * 8);
        }
        __syncthreads();
    }
}

// ---- grouped GEMM 2: 256x128 tile, BK=64, 2-slot dbuf, counted vmcnt (6 in flight): ybuf = gate*(mid@w2[e]+b2[e]) ----
// 8 waves of 64x64 (4Mx2N); 6 gld_lds/thread/K-tile
__global__ __launch_bounds__(512, 2) void k_ffn2(
    const unsigned short* __restrict__ mid, const unsigned short* __restrict__ w2t,
    const float* __restrict__ b2, const int* __restrict__ ctl, const int* __restrict__ tiles,
    const float* __restrict__ rgte, unsigned short* __restrict__ ybuf) {
    // 4 n-tiles of one m-tile share c8 (same XCD L2 holds the mid rows)
    int flat = blockIdx.x;
    int c8 = flat & 7, q = flat >> 3;
    int nt = q & 3, mt = (q >> 2) * 8 + c8;
    if (mt >= ctl[13]) return;
    int tv = tiles[mt];
    int e = tv >> 16, m0 = tv & 0xFFFF;
    int base = ctl[8 + e];
    int cnt = ctl[9 + e] - base;
    int n0 = nt * 128;

    __shared__ unsigned short sm[2 * SLOT2];   // 96 KB dbuf; epilogue repack (256 x RP2) aliases
    __shared__ float gts[256];

    int t = threadIdx.x;
    if (t < 256) {
        int r = m0 + t; if (r >= cnt) r = cnt - 1;
        gts[t] = rgte[base + r];
    }
    __syncthreads();

    const unsigned short* wB = w2t + (size_t)e * DD * HH;
    const unsigned short* gA[4]; const unsigned short* gB[2];
    int lofA[4], lofB[2];
#pragma unroll
    for (int r = 0; r < 4; r++) {
        int idx = r * 512 + t;
        int row = idx >> 3, sch = idx & 7;
        int cg = (sch - row) & 7;
        int ra = m0 + row; if (ra >= cnt) ra = cnt - 1;
        gA[r] = mid + (size_t)(base + ra) * HH + cg * 8;
        lofA[r] = idx * 8;
    }
#pragma unroll
    for (int r = 0; r < 2; r++) {
        int idx = r * 512 + t;
        int row = idx >> 3, sch = idx & 7;
        int cg = (sch - row) & 7;
        gB[r] = wB + (size_t)(n0 + row) * HH + cg * 8;
        lofB[r] = ASZ2 + idx * 8;
    }

    int w = t >> 6, lane = t & 63;
    int wm = (w >> 1) * 64, wn = (w & 1) * 64;   // wave tile 64x64
    int lrow = lane & 15, quad = lane >> 4;

    floatx4 acc[4][4];
#pragma unroll
    for (int i = 0; i < 4; i++)
#pragma unroll
        for (int j = 0; j < 4; j++) acc[i][j] = (floatx4)0.f;

    // prologue: stage K-tile 0 into slot 0
#pragma unroll
    for (int r = 0; r < 4; r++) gld_lds16(gA[r], sm + lofA[r]);
#pragma unroll
    for (int r = 0; r < 2; r++) gld_lds16(gB[r], sm + lofB[r]);

    const int NK = HH / 64;   // 32
    for (int tt = 0; tt < NK; tt++) {
        if (tt + 1 < NK) {
            unsigned short* sb = sm + ((tt + 1) & 1) * SLOT2;
            int k0 = (tt + 1) * 64;
#pragma unroll
            for (int r = 0; r < 4; r++) gld_lds16(gA[r] + k0, sb + lofA[r]);
#pragma unroll
            for (int r = 0; r < 2; r++) gld_lds16(gB[r] + k0, sb + lofB[r]);
            asm volatile("s_waitcnt vmcnt(6)" ::: "memory");
        } else {
            asm volatile("s_waitcnt vmcnt(0)" ::: "memory");
        }
        __builtin_amdgcn_s_barrier();
        asm volatile("" ::: "memory");
        const unsigned short* SA = sm + (tt & 1) * SLOT2;
        const unsigned short* SB = SA + ASZ2;
#pragma unroll
        for (int ks = 0; ks < 2; ks++) {
            short8 af[4], bf[4];
#pragma unroll
            for (int i = 0; i < 4; i++) {
                int row = wm + 16 * i + lrow;
                af[i] = *(const short8*)&SA[row * 64 + (((ks << 2) + quad + row) & 7) * 8];
            }
#pragma unroll
            for (int j = 0; j < 4; j++) {
                int row = wn + 16 * j + lrow;
                bf[j] = *(const short8*)&SB[row * 64 + (((ks << 2) + quad + row) & 7) * 8];
            }
            __builtin_amdgcn_s_setprio(1);
#pragma unroll
            for (int i = 0; i < 4; i++)
#pragma unroll
                for (int j = 0; j < 4; j++)
                    acc[i][j] = __builtin_amdgcn_mfma_f32_16x16x32_bf16(af[i], bf[j], acc[i][j], 0, 0, 0);
            __builtin_amdgcn_s_setprio(0);
        }
        asm volatile("" ::: "memory");
        __builtin_amdgcn_s_barrier();
        asm volatile("" ::: "memory");
    }
    __syncthreads();

    // epilogue: bias + gate-scale -> repack (single pass, 256 x RP2) -> coalesced stores
    float b2v[4];
#pragma unroll
    for (int j = 0; j < 4; j++) b2v[j] = b2[e * DD + n0 + wn + 16 * j + lrow];
#pragma unroll
    for (int j = 0; j < 4; j++) {
        int col = wn + 16 * j + lrow;
#pragma unroll
        for (int i = 0; i < 4; i++) {
#pragma unroll
            for (int r = 0; r < 4; r++) {
                int m = wm + 16 * i + quad * 4 + r;
                float v = (acc[i][j][r] + b2v[j]) * gts[m];
                sm[m * RP2 + col] = f2bf(v);
            }
        }
    }
    __syncthreads();
    {
        int row = t >> 1, half = t & 1;   // 256 rows x 2 segs of 128B
        if (m0 + row < cnt) {
            unsigned short* dst = ybuf + (size_t)(base + m0 + row) * DD + n0 + half * 64;
            const unsigned short* src = sm + row * RP2 + half * 64;
#pragma unroll
            for (int k = 0; k < 8; k++)
                *(uint4*)(dst + k * 8) = *(const uint4*)(src + k * 8);
        }
    }
}

// ---------------- combine (512 thr, 4 tokens/block): out[n] = ybuf[slot(n,0)] + ybuf[slot(n,1)] ----------------
__global__ __launch_bounds__(512) void k_combine(const unsigned short* __restrict__ ybuf,
                                                 const int* __restrict__ slotof,
                                                 float* __restrict__ out) {
    int n = blockIdx.x * 4 + (threadIdx.x >> 7);
    int c = (threadIdx.x & 127) * 4;
    int sA = slotof[2 * n], sB = slotof[2 * n + 1];
    ushort4 a = *(const ushort4*)(ybuf + (size_t)sA * DD + c);
    ushort4 b = *(const ushort4*)(ybuf + (size_t)sB * DD + c);
    float4 o;
    o.x = bf2f(a.x) + bf2f(b.x);
    o.y = bf2f(a.y) + bf2f(b.y);
    o.z = bf2f(a.z) + bf2f(b.z);
    o.w = bf2f(a.w) + bf2f(b.w);
    *(float4*)(out + (size_t)n * DD + c) = o;
}

extern "C" void kernel_launch(void* const* d_in, const int* in_sizes, int n_in,
                              void* d_out, int out_size, void* d_ws, size_t ws_size,
                              hipStream_t stream) {
    const float* h  = (const float*)d_in[0];
    const float* wg = (const float*)d_in[1];
    const float* w1 = (const float*)d_in[2];
    const float* b1 = (const float*)d_in[3];
    const float* w2 = (const float*)d_in[4];
    const float* b2 = (const float*)d_in[5];
    float* out = (float*)d_out;

    char* ws = (char*)d_ws;
    size_t off = 0;
    auto alloc = [&](size_t bytes) -> void* {
        void* p = ws + off;
        off += (bytes + 255) & ~(size_t)255;
        return p;
    };
    unsigned short* hb  = (unsigned short*)alloc((size_t)NT * DD * 2);        // dead after ffn1
    unsigned short* w1t = (unsigned short*)alloc((size_t)NE * HH * DD * 2);   // dead after ffn1
    unsigned short* w2t = (unsigned short*)alloc((size_t)NE * DD * HH * 2);
    int*   sel    = (int*)alloc((size_t)NT * 2 * 4);
    float* gv     = (float*)alloc((size_t)NT * 2 * 4);
    int*   ctl    = (int*)alloc(256);
    int*   tiles  = (int*)alloc(1024);
    int*   rtok   = (int*)alloc((size_t)NT * 2 * 4);
    float* rgte   = (float*)alloc((size_t)NT * 2 * 4);
    int*   slotof = (int*)alloc((size_t)NT * 2 * 4);
    unsigned short* mid = (unsigned short*)alloc((size_t)NT * 2 * HH * 2);
    // ybuf [NT*2][DD] bf16 (16.7 MB) aliases hb+w1t (16.7 MB), both dead before ffn2 runs
    unsigned short* ybuf = (unsigned short*)ws;

    k_prep<<<dim3(4096 + NT / 8), 512, 0, stream>>>(w1, w1t, w2, w2t, h, wg, sel, gv, hb);
    k_scan<<<1, 1024, 0, stream>>>(sel, gv, ctl, rtok, rgte, slotof, tiles);
    k_ffn1<<<dim3(FFN1_GRID), 512, 0, stream>>>(hb, w1t, b1, ctl, tiles, rtok, mid);
    k_ffn2<<<dim3(FFN2_GRID), 512, 0, stream>>>(mid, w2t, b2, ctl, tiles, rgte, ybuf);
    k_combine<<<dim3(NT / 4), 512, 0, stream>>>(ybuf, slotof, out);
}

// Round 3
// 256.435 us; speedup vs baseline: 1.1969x; 1.0945x over previous
//
#include <hip/hip_runtime.h>
#include <hip/hip_bf16.h>
#include <cstdint>
#include <cstddef>

// Problem constants
#define NT 8192
#define DD 512
#define HH 2048
#define NE 4
// ffn1: BM=256,BN=256,BK=64, 2-slot dbuf (128 KB, 1 blk/CU), counted vmcnt(8)
#define SLOT1 32768    // shorts: A 256x64 + B 256x64
#define ASZ1  16384
// ffn2: BM=128,BN=128,BK=64, 2-slot dbuf (64 KB, 2 blk/CU), counted vmcnt(4)
#define SLOT2 16384    // shorts: A 128x64 + B 128x64
#define ASZ2  8192
#define RP1 264        // ffn1 repack row stride (shorts)
#define RP2 136        // ffn2 repack row stride (shorts)
#define FFN1_GRID 576  // 9 mt-groups x 8 xcd x 8 n-tiles (covers <=67 m-tiles of 256)
#define FFN2_GRID 544  // 17 mt-groups x 8 xcd x 4 n-tiles (covers <=131 m-tiles of 128)

typedef short short8 __attribute__((ext_vector_type(8)));
typedef float floatx4 __attribute__((ext_vector_type(4)));

static __device__ __forceinline__ unsigned short f2bf(float f) {
    union { float f; uint32_t u; } v; v.f = f;
    uint32_t u = v.u;
    u += 0x7FFFu + ((u >> 16) & 1u);   // round-to-nearest-even
    return (unsigned short)(u >> 16);
}
static __device__ __forceinline__ float bf2f(unsigned short u) {
    union { uint32_t u; float f; } v; v.u = ((uint32_t)u) << 16; return v.f;
}

// async global->LDS, 16B per lane. LDS dest = wave-uniform base + lane*16 (addresses below are lane-linear).
static __device__ __forceinline__ void gld_lds16(const unsigned short* g, unsigned short* l) {
    __builtin_amdgcn_global_load_lds(
        (const __attribute__((address_space(1))) void*)g,
        (__attribute__((address_space(3))) void*)l, 16, 0, 0);
}

// ------------- merged prep (512 thr): weight transpose+cast (blocks 0..2047) + gate (2048..) -------------
// transpose tile 64x64 via col-major LDS (S=65): float4 global loads, conflict-free scalar LDS ops,
// uint4 (8xbf16) global stores. All global access 16B/lane.
__global__ __launch_bounds__(512) void k_prep(
    const float* __restrict__ w1, unsigned short* __restrict__ w1t,
    const float* __restrict__ w2, unsigned short* __restrict__ w2t,
    const float* __restrict__ h, const float* __restrict__ wg,
    int* __restrict__ sel, float* __restrict__ gv, unsigned short* __restrict__ hb) {
    int t = threadIdx.x;
    if (blockIdx.x < 2048) {
        int z = blockIdx.x >> 8;            // 256 blocks per expert-matrix
        int rem = blockIdx.x & 255;
        const float* in; unsigned short* out; int R, C, by, bx;
        if (z < 4) {
            in = w1 + (size_t)z * DD * HH; out = w1t + (size_t)z * DD * HH;
            R = DD; C = HH; by = rem >> 5; bx = rem & 31;      // 8 x 32 tiles
        } else {
            in = w2 + (size_t)(z - 4) * HH * DD; out = w2t + (size_t)(z - 4) * HH * DD;
            R = HH; C = DD; by = rem >> 3; bx = rem & 7;       // 32 x 8 tiles
        }
        int r0 = by * 64, c0 = bx * 64;
        __shared__ float tl[64 * 65];       // tl[c*65 + r] (col-major, S=65 -> conflict-free)
        int rr = t >> 4, c4 = (t & 15) * 4;
#pragma unroll
        for (int p = 0; p < 2; p++) {
            int r = rr + p * 32;
            float4 v = *(const float4*)(in + (size_t)(r0 + r) * C + c0 + c4);
            tl[(c4 + 0) * 65 + r] = v.x;
            tl[(c4 + 1) * 65 + r] = v.y;
            tl[(c4 + 2) * 65 + r] = v.z;
            tl[(c4 + 3) * 65 + r] = v.w;
        }
        __syncthreads();
        int c = t >> 3, seg = t & 7;
        unsigned short tmp[8];
#pragma unroll
        for (int k = 0; k < 8; k++) tmp[k] = f2bf(tl[c * 65 + seg * 8 + k]);
        *(uint4*)(out + (size_t)(c0 + c) * R + r0 + seg * 8) = *(const uint4*)tmp;
        return;
    }
    // ---- gating: fp32 logits, exact top-2, softmax over top-2, fused h->bf16 cast (8 tokens/block) ----
    int wid = t >> 6, lane = t & 63;
    int n = (blockIdx.x - 2048) * 8 + wid;
    const float* hr = h + (size_t)n * DD;
    int d0 = lane * 8;
    float hv[8];
    *(float4*)(hv)     = *(const float4*)(hr + d0);
    *(float4*)(hv + 4) = *(const float4*)(hr + d0 + 4);
    unsigned short tmp[8];
#pragma unroll
    for (int j = 0; j < 8; j++) tmp[j] = f2bf(hv[j]);
    *(uint4*)(hb + (size_t)n * DD + d0) = *(const uint4*)tmp;

    float a0 = 0.f, a1 = 0.f, a2 = 0.f, a3 = 0.f;
#pragma unroll
    for (int j = 0; j < 8; j++) {
        float4 w = *(const float4*)(wg + (size_t)(d0 + j) * 4);
        a0 += hv[j] * w.x; a1 += hv[j] * w.y; a2 += hv[j] * w.z; a3 += hv[j] * w.w;
    }
#pragma unroll
    for (int off = 32; off; off >>= 1) {
        a0 += __shfl_xor(a0, off);
        a1 += __shfl_xor(a1, off);
        a2 += __shfl_xor(a2, off);
        a3 += __shfl_xor(a3, off);
    }
    if (lane == 0) {
        float v[4] = {a0, a1, a2, a3};
        int e0 = 0; float b = v[0];
#pragma unroll
        for (int e = 1; e < 4; e++) if (v[e] > b) { b = v[e]; e0 = e; }
        int e1 = -1; float b2 = -1e30f;
#pragma unroll
        for (int e = 0; e < 4; e++) if (e != e0 && v[e] > b2) { b2 = v[e]; e1 = e; }
        float x = expf(b2 - b);
        float s = 1.f + x;
        sel[2 * n] = e0; sel[2 * n + 1] = e1;
        gv[2 * n] = 1.f / s; gv[2 * n + 1] = x / s;
    }
}

// ---------------- single-block scan (1024 thr): shfl scans + LDS-staged coalesced outputs ----------------
// ctl: [8..11]=expert base, [12]=total, [13]=n256 tiles, [14]=n128 tiles
// rtok[s] = 2*n+k (idx); slotof[idx] = s. (gate value fetched later as gv[rtok[s]])
__global__ __launch_bounds__(1024) void k_scan(const int* __restrict__ sel,
                                               int* __restrict__ ctl, int* __restrict__ rtok,
                                               int* __restrict__ slotof,
                                               int* __restrict__ tiles, int* __restrict__ tiles2) {
    __shared__ int wtot[4][16];
    __shared__ int wbase[4][16];
    __shared__ int ebase[4];
    __shared__ int sL[16384];
    int t = threadIdx.x, w = t >> 6, lane = t & 63;
    int c[4] = {0, 0, 0, 0};
    int selloc[16];
    const int4* s4 = (const int4*)sel;
#pragma unroll
    for (int i = 0; i < 4; i++) {
        int4 v = s4[t * 4 + i];
        selloc[i * 4 + 0] = v.x; c[v.x]++;
        selloc[i * 4 + 1] = v.y; c[v.y]++;
        selloc[i * 4 + 2] = v.z; c[v.z]++;
        selloc[i * 4 + 3] = v.w; c[v.w]++;
    }
    int inc[4] = {c[0], c[1], c[2], c[3]};
#pragma unroll
    for (int off = 1; off < 64; off <<= 1) {
#pragma unroll
        for (int e = 0; e < 4; e++) {
            int v = __shfl_up(inc[e], off);
            if (lane >= off) inc[e] += v;
        }
    }
    if (lane == 63)
#pragma unroll
        for (int e = 0; e < 4; e++) wtot[e][w] = inc[e];
    __syncthreads();
    if (t == 0) {
        int o = 0, n256 = 0, n128 = 0;
#pragma unroll
        for (int e = 0; e < 4; e++) {
            int s = 0;
            for (int ww = 0; ww < 16; ww++) { wbase[e][ww] = s; s += wtot[e][ww]; }
            ebase[e] = o; ctl[8 + e] = o;
            for (int m0 = 0; m0 < s; m0 += 256) tiles[n256++] = (e << 16) | m0;
            for (int m0 = 0; m0 < s; m0 += 128) tiles2[n128++] = (e << 16) | m0;
            o += s;
        }
        ctl[12] = o; ctl[13] = n256; ctl[14] = n128;
    }
    __syncthreads();
    int pos[4];
#pragma unroll
    for (int e = 0; e < 4; e++) pos[e] = ebase[e] + wbase[e][w] + inc[e] - c[e];  // exclusive
    int slots[16];
#pragma unroll
    for (int i = 0; i < 16; i++) slots[i] = pos[selloc[i]]++;
    // slotof: coalesced int4 direct stores
#pragma unroll
    for (int i = 0; i < 4; i++) {
        int4 v; v.x = slots[4 * i]; v.y = slots[4 * i + 1]; v.z = slots[4 * i + 2]; v.w = slots[4 * i + 3];
        *(int4*)&slotof[t * 16 + i * 4] = v;
    }
    // rtok: scatter to LDS, then coalesced dump
#pragma unroll
    for (int i = 0; i < 16; i++) sL[slots[i]] = t * 16 + i;
    __syncthreads();
#pragma unroll
    for (int p = 0; p < 4; p++)
        *(int4*)&rtok[p * 4096 + t * 4] = *(const int4*)&sL[p * 4096 + t * 4];
}

// ---- grouped GEMM 1: 256x256 tile, BK=64, 2-slot dbuf, counted vmcnt (8 in flight across barriers) ----
// mid = relu(gather(h) @ w1[e] + b1[e]); 8 waves of 128x64 (2Mx4N); 8 gld_lds/thread/K-tile
__global__ __launch_bounds__(512, 2) void k_ffn1(
    const unsigned short* __restrict__ hb, const unsigned short* __restrict__ w1t,
    const float* __restrict__ b1, const int* __restrict__ ctl, const int* __restrict__ tiles,
    const int* __restrict__ rtok, unsigned short* __restrict__ mid) {
    // flat -> (xcd c8, m-tile, n-tile): 8 n-tiles of one m-tile share c8 (same XCD L2 holds A rows)
    int flat = blockIdx.x;
    int c8 = flat & 7, q = flat >> 3;
    int nt = q & 7, mt = (q >> 3) * 8 + c8;
    if (mt >= ctl[13]) return;
    int tv = tiles[mt];
    int e = tv >> 16, m0 = tv & 0xFFFF;
    int base = ctl[8 + e];
    int cnt = ctl[9 + e] - base;
    int n0 = nt * 256;

    __shared__ unsigned short sm[2 * SLOT1];   // 128 KB dbuf; epilogue repack aliases (128 x RP1 per half)
    __shared__ int toks[256];

    int t = threadIdx.x;
    if (t < 256) {
        int r = m0 + t; if (r >= cnt) r = cnt - 1;
        toks[t] = rtok[base + r] >> 1;
    }
    __syncthreads();

    const unsigned short* wB = w1t + (size_t)e * HH * DD;
    // staging: 4 rounds cover 256 rows x 8 granules of 16B; src granule pre-rotated by row (proven layout)
    const unsigned short* gA[4]; const unsigned short* gB[4];
    int lof[4];
#pragma unroll
    for (int r = 0; r < 4; r++) {
        int idx = r * 512 + t;
        int row = idx >> 3, sch = idx & 7;
        int cg = (sch - row) & 7;
        gA[r] = hb + (size_t)toks[row] * DD + cg * 8;
        gB[r] = wB + (size_t)(n0 + row) * DD + cg * 8;
        lof[r] = idx * 8;                      // = row*64 + sch*8, lane-linear within a wave
    }

    int w = t >> 6, lane = t & 63;
    int wm = (w >> 2) * 128, wn = (w & 3) * 64;   // wave tile 128x64
    int lrow = lane & 15, quad = lane >> 4;

    floatx4 acc[8][4];
#pragma unroll
    for (int i = 0; i < 8; i++)
#pragma unroll
        for (int j = 0; j < 4; j++) acc[i][j] = (floatx4)0.f;

    // prologue: stage K-tile 0 into slot 0
#pragma unroll
    for (int r = 0; r < 4; r++) {
        gld_lds16(gA[r], sm + lof[r]);
        gld_lds16(gB[r], sm + ASZ1 + lof[r]);
    }

    const int NK = DD / 64;   // 8
    for (int tt = 0; tt < NK; tt++) {
        // issue next tile into the other slot (fully read in iter tt-1, barrier-protected),
        // then counted wait: only tile tt's 8 loads must land; the 8 just issued stay in flight.
        if (tt + 1 < NK) {
            unsigned short* sb = sm + ((tt + 1) & 1) * SLOT1;
            int k0 = (tt + 1) * 64;
#pragma unroll
            for (int r = 0; r < 4; r++) {
                gld_lds16(gA[r] + k0, sb + lof[r]);
                gld_lds16(gB[r] + k0, sb + ASZ1 + lof[r]);
            }
            asm volatile("s_waitcnt vmcnt(8)" ::: "memory");
        } else {
            asm volatile("s_waitcnt vmcnt(0)" ::: "memory");
        }
        __builtin_amdgcn_s_barrier();
        asm volatile("" ::: "memory");
        const unsigned short* SA = sm + (tt & 1) * SLOT1;
        const unsigned short* SB = SA + ASZ1;
#pragma unroll
        for (int ks = 0; ks < 2; ks++) {
            short8 af[8], bf[4];
#pragma unroll
            for (int i = 0; i < 8; i++) {
                int row = wm + 16 * i + lrow;
                af[i] = *(const short8*)&SA[row * 64 + (((ks << 2) + quad + row) & 7) * 8];
            }
#pragma unroll
            for (int j = 0; j < 4; j++) {
                int row = wn + 16 * j + lrow;
                bf[j] = *(const short8*)&SB[row * 64 + (((ks << 2) + quad + row) & 7) * 8];
            }
            __builtin_amdgcn_s_setprio(1);
#pragma unroll
            for (int i = 0; i < 8; i++)
#pragma unroll
                for (int j = 0; j < 4; j++)
                    acc[i][j] = __builtin_amdgcn_mfma_f32_16x16x32_bf16(af[i], bf[j], acc[i][j], 0, 0, 0);
            __builtin_amdgcn_s_setprio(0);
        }
        asm volatile("" ::: "memory");
        __builtin_amdgcn_s_barrier();
        asm volatile("" ::: "memory");
    }
    __syncthreads();   // full drain before repack aliases the slots

    // epilogue: bias + relu -> repack (two 128-row passes) -> coalesced 128B stores
    float bias[4];
#pragma unroll
    for (int j = 0; j < 4; j++) bias[j] = b1[e * HH + n0 + wn + 16 * j + lrow];
#pragma unroll
    for (int half = 0; half < 2; half++) {
        if ((w >> 2) == half) {
#pragma unroll
            for (int j = 0; j < 4; j++) {
                int col = wn + 16 * j + lrow;
#pragma unroll
                for (int i = 0; i < 8; i++) {
#pragma unroll
                    for (int r = 0; r < 4; r++) {
                        int lm = 16 * i + quad * 4 + r;    // local row within half
                        float v = acc[i][j][r] + bias[j];
                        v = v > 0.f ? v : 0.f;
                        sm[lm * RP1 + col] = f2bf(v);
                    }
                }
            }
        }
        __syncthreads();
        int row = t >> 2, seg = t & 3;    // 128 rows x 4 segs of 128B
        int grow = half * 128 + row;
        if (m0 + grow < cnt) {
            unsigned short* dst = mid + (size_t)(base + m0 + grow) * HH + n0 + seg * 64;
            const unsigned short* src = sm + row * RP1 + seg * 64;
#pragma unroll
            for (int k = 0; k < 8; k++)
                *(uint4*)(dst + k * 8) = *(const uint4*)(src + k * 8);
        }
        __syncthreads();
    }
}

// ---- grouped GEMM 2: 128x128 tile, BK=64, 2-slot dbuf (64 KB -> 2 blk/CU), counted vmcnt(4) ----
// ybuf[slot] = gate * (mid @ w2[e] + b2[e]); 8 waves of 32x64 (4Mx2N); 4 gld_lds/thread/K-tile
__global__ __launch_bounds__(512, 2) void k_ffn2(
    const unsigned short* __restrict__ mid, const unsigned short* __restrict__ w2t,
    const float* __restrict__ b2, const int* __restrict__ ctl, const int* __restrict__ tiles2,
    const float* __restrict__ gv, const int* __restrict__ rtok, unsigned short* __restrict__ ybuf) {
    // 4 n-tiles of one m-tile share c8 (same XCD L2 holds the mid rows)
    int flat = blockIdx.x;
    int c8 = flat & 7, q = flat >> 3;
    int nt = q & 3, mt = (q >> 2) * 8 + c8;
    if (mt >= ctl[14]) return;
    int tv = tiles2[mt];
    int e = tv >> 16, m0 = tv & 0xFFFF;
    int base = ctl[8 + e];
    int cnt = ctl[9 + e] - base;
    int n0 = nt * 128;

    __shared__ unsigned short sm[2 * SLOT2];   // 64 KB dbuf; epilogue repack (128 x RP2) aliases
    __shared__ float gts[128];

    int t = threadIdx.x;
    if (t < 128) {
        int r = m0 + t; if (r >= cnt) r = cnt - 1;
        gts[t] = gv[rtok[base + r]];
    }
    __syncthreads();

    const unsigned short* wB = w2t + (size_t)e * DD * HH;
    const unsigned short* gA[2]; const unsigned short* gB[2];
    int lofA[2], lofB[2];
#pragma unroll
    for (int r = 0; r < 2; r++) {
        int idx = r * 512 + t;
        int row = idx >> 3, sch = idx & 7;
        int cg = (sch - row) & 7;
        int ra = m0 + row; if (ra >= cnt) ra = cnt - 1;
        gA[r] = mid + (size_t)(base + ra) * HH + cg * 8;
        lofA[r] = idx * 8;
        gB[r] = wB + (size_t)(n0 + row) * HH + cg * 8;
        lofB[r] = ASZ2 + idx * 8;
    }

    int w = t >> 6, lane = t & 63;
    int wm = (w & 3) * 32, wn = (w >> 2) * 64;   // wave tile 32x64
    int lrow = lane & 15, quad = lane >> 4;

    floatx4 acc[2][4];
#pragma unroll
    for (int i = 0; i < 2; i++)
#pragma unroll
        for (int j = 0; j < 4; j++) acc[i][j] = (floatx4)0.f;

    // prologue: stage K-tile 0 into slot 0
#pragma unroll
    for (int r = 0; r < 2; r++) {
        gld_lds16(gA[r], sm + lofA[r]);
        gld_lds16(gB[r], sm + lofB[r]);
    }

    const int NK = HH / 64;   // 32
    for (int tt = 0; tt < NK; tt++) {
        if (tt + 1 < NK) {
            unsigned short* sb = sm + ((tt + 1) & 1) * SLOT2;
            int k0 = (tt + 1) * 64;
#pragma unroll
            for (int r = 0; r < 2; r++) {
                gld_lds16(gA[r] + k0, sb + lofA[r]);
                gld_lds16(gB[r] + k0, sb + lofB[r]);
            }
            asm volatile("s_waitcnt vmcnt(4)" ::: "memory");
        } else {
            asm volatile("s_waitcnt vmcnt(0)" ::: "memory");
        }
        __builtin_amdgcn_s_barrier();
        asm volatile("" ::: "memory");
        const unsigned short* SA = sm + (tt & 1) * SLOT2;
        const unsigned short* SB = SA + ASZ2;
#pragma unroll
        for (int ks = 0; ks < 2; ks++) {
            short8 af[2], bf[4];
#pragma unroll
            for (int i = 0; i < 2; i++) {
                int row = wm + 16 * i + lrow;
                af[i] = *(const short8*)&SA[row * 64 + (((ks << 2) + quad + row) & 7) * 8];
            }
#pragma unroll
            for (int j = 0; j < 4; j++) {
                int row = wn + 16 * j + lrow;
                bf[j] = *(const short8*)&SB[row * 64 + (((ks << 2) + quad + row) & 7) * 8];
            }
            __builtin_amdgcn_s_setprio(1);
#pragma unroll
            for (int i = 0; i < 2; i++)
#pragma unroll
                for (int j = 0; j < 4; j++)
                    acc[i][j] = __builtin_amdgcn_mfma_f32_16x16x32_bf16(af[i], bf[j], acc[i][j], 0, 0, 0);
            __builtin_amdgcn_s_setprio(0);
        }
        asm volatile("" ::: "memory");
        __builtin_amdgcn_s_barrier();
        asm volatile("" ::: "memory");
    }
    __syncthreads();

    // epilogue: bias + gate-scale -> repack (128 x RP2) -> coalesced stores
    float b2v[4];
#pragma unroll
    for (int j = 0; j < 4; j++) b2v[j] = b2[e * DD + n0 + wn + 16 * j + lrow];
#pragma unroll
    for (int j = 0; j < 4; j++) {
        int col = wn + 16 * j + lrow;
#pragma unroll
        for (int i = 0; i < 2; i++) {
#pragma unroll
            for (int r = 0; r < 4; r++) {
                int m = wm + 16 * i + quad * 4 + r;
                float v = (acc[i][j][r] + b2v[j]) * gts[m];
                sm[m * RP2 + col] = f2bf(v);
            }
        }
    }
    __syncthreads();
    {
        int row = t >> 2, q4 = t & 3;   // 128 rows x 4 chunks of 32 elems
        if (m0 + row < cnt) {
            unsigned short* dst = ybuf + (size_t)(base + m0 + row) * DD + n0 + q4 * 32;
            const unsigned short* src = sm + row * RP2 + q4 * 32;
#pragma unroll
            for (int it = 0; it < 4; it++)
                *(uint4*)(dst + it * 8) = *(const uint4*)(src + it * 8);
        }
    }
}

// ---------------- combine (512 thr, 4 tokens/block): out[n] = ybuf[slot(n,0)] + ybuf[slot(n,1)] ----------------
__global__ __launch_bounds__(512) void k_combine(const unsigned short* __restrict__ ybuf,
                                                 const int* __restrict__ slotof,
                                                 float* __restrict__ out) {
    int n = blockIdx.x * 4 + (threadIdx.x >> 7);
    int c = (threadIdx.x & 127) * 4;
    int sA = slotof[2 * n], sB = slotof[2 * n + 1];
    ushort4 a = *(const ushort4*)(ybuf + (size_t)sA * DD + c);
    ushort4 b = *(const ushort4*)(ybuf + (size_t)sB * DD + c);
    float4 o;
    o.x = bf2f(a.x) + bf2f(b.x);
    o.y = bf2f(a.y) + bf2f(b.y);
    o.z = bf2f(a.z) + bf2f(b.z);
    o.w = bf2f(a.w) + bf2f(b.w);
    *(float4*)(out + (size_t)n * DD + c) = o;
}

extern "C" void kernel_launch(void* const* d_in, const int* in_sizes, int n_in,
                              void* d_out, int out_size, void* d_ws, size_t ws_size,
                              hipStream_t stream) {
    const float* h  = (const float*)d_in[0];
    const float* wg = (const float*)d_in[1];
    const float* w1 = (const float*)d_in[2];
    const float* b1 = (const float*)d_in[3];
    const float* w2 = (const float*)d_in[4];
    const float* b2 = (const float*)d_in[5];
    float* out = (float*)d_out;

    char* ws = (char*)d_ws;
    size_t off = 0;
    auto alloc = [&](size_t bytes) -> void* {
        void* p = ws + off;
        off += (bytes + 255) & ~(size_t)255;
        return p;
    };
    unsigned short* hb  = (unsigned short*)alloc((size_t)NT * DD * 2);        // dead after ffn1
    unsigned short* w1t = (unsigned short*)alloc((size_t)NE * HH * DD * 2);   // dead after ffn1
    unsigned short* w2t = (unsigned short*)alloc((size_t)NE * DD * HH * 2);
    int*   sel    = (int*)alloc((size_t)NT * 2 * 4);
    float* gv     = (float*)alloc((size_t)NT * 2 * 4);
    int*   ctl    = (int*)alloc(256);
    int*   tiles  = (int*)alloc(1024);
    int*   tiles2 = (int*)alloc(2048);
    int*   rtok   = (int*)alloc((size_t)NT * 2 * 4);
    int*   slotof = (int*)alloc((size_t)NT * 2 * 4);
    unsigned short* mid = (unsigned short*)alloc((size_t)NT * 2 * HH * 2);
    // ybuf [NT*2][DD] bf16 (16.7 MB) aliases hb+w1t (16.7 MB), both dead before ffn2 runs
    unsigned short* ybuf = (unsigned short*)ws;

    k_prep<<<dim3(2048 + NT / 8), 512, 0, stream>>>(w1, w1t, w2, w2t, h, wg, sel, gv, hb);
    k_scan<<<1, 1024, 0, stream>>>(sel, ctl, rtok, slotof, tiles, tiles2);
    k_ffn1<<<dim3(FFN1_GRID), 512, 0, stream>>>(hb, w1t, b1, ctl, tiles, rtok, mid);
    k_ffn2<<<dim3(FFN2_GRID), 512, 0, stream>>>(mid, w2t, b2, ctl, tiles2, gv, rtok, ybuf);
    k_combine<<<dim3(NT / 4), 512, 0, stream>>>(ybuf, slotof, out);
}

// Round 4
// 243.259 us; speedup vs baseline: 1.2618x; 1.0542x over previous
//
#include <hip/hip_runtime.h>
#include <hip/hip_bf16.h>
#include <cstdint>
#include <cstddef>

// Problem constants
#define NT 8192
#define DD 512
#define HH 2048
#define NE 4
// ffn1: BM=256,BN=256,BK=64, 2-slot dbuf (128 KB), 4-phase interleave, chunk-counted vmcnt
#define SLOT1 32768    // shorts: A 256x64 + B 256x64
#define ASZ1  16384
// ffn2: BM=128,BN=128,BK=64, 2-slot dbuf (64 KB, 2 blk/CU), pre-issue + vmcnt(2)
#define SLOT2 16384    // shorts: A 128x64 + B 128x64
#define ASZ2  8192
#define RP1 264        // ffn1 repack row stride (shorts)
#define RP2 136        // ffn2 repack row stride (shorts)
#define FFN1_GRID 576  // 9 mt-groups x 8 xcd x 8 n-tiles (covers <=67 m-tiles of 256)
#define FFN2_GRID 544  // 17 mt-groups x 8 xcd x 4 n-tiles (covers <=131 m-tiles of 128)

typedef short short8 __attribute__((ext_vector_type(8)));
typedef float floatx4 __attribute__((ext_vector_type(4)));

static __device__ __forceinline__ unsigned short f2bf(float f) {
    union { float f; uint32_t u; } v; v.f = f;
    uint32_t u = v.u;
    u += 0x7FFFu + ((u >> 16) & 1u);   // round-to-nearest-even
    return (unsigned short)(u >> 16);
}
static __device__ __forceinline__ float bf2f(unsigned short u) {
    union { uint32_t u; float f; } v; v.u = ((uint32_t)u) << 16; return v.f;
}

// async global->LDS, 16B per lane. LDS dest = wave-uniform base + lane*16 (addresses below are lane-linear).
static __device__ __forceinline__ void gld_lds16(const unsigned short* g, unsigned short* l) {
    __builtin_amdgcn_global_load_lds(
        (const __attribute__((address_space(1))) void*)g,
        (__attribute__((address_space(3))) void*)l, 16, 0, 0);
}

// ------------- merged prep (512 thr): weight transpose+cast (blocks 0..2047) + gate (2048..) -------------
__global__ __launch_bounds__(512) void k_prep(
    const float* __restrict__ w1, unsigned short* __restrict__ w1t,
    const float* __restrict__ w2, unsigned short* __restrict__ w2t,
    const float* __restrict__ h, const float* __restrict__ wg,
    int* __restrict__ sel, float* __restrict__ gv, unsigned short* __restrict__ hb) {
    int t = threadIdx.x;
    if (blockIdx.x < 2048) {
        int z = blockIdx.x >> 8;            // 256 blocks per expert-matrix
        int rem = blockIdx.x & 255;
        const float* in; unsigned short* out; int R, C, by, bx;
        if (z < 4) {
            in = w1 + (size_t)z * DD * HH; out = w1t + (size_t)z * DD * HH;
            R = DD; C = HH; by = rem >> 5; bx = rem & 31;      // 8 x 32 tiles
        } else {
            in = w2 + (size_t)(z - 4) * HH * DD; out = w2t + (size_t)(z - 4) * HH * DD;
            R = HH; C = DD; by = rem >> 3; bx = rem & 7;       // 32 x 8 tiles
        }
        int r0 = by * 64, c0 = bx * 64;
        __shared__ float tl[64 * 65];       // tl[c*65 + r] (col-major, S=65 -> conflict-free)
        int rr = t >> 4, c4 = (t & 15) * 4;
#pragma unroll
        for (int p = 0; p < 2; p++) {
            int r = rr + p * 32;
            float4 v = *(const float4*)(in + (size_t)(r0 + r) * C + c0 + c4);
            tl[(c4 + 0) * 65 + r] = v.x;
            tl[(c4 + 1) * 65 + r] = v.y;
            tl[(c4 + 2) * 65 + r] = v.z;
            tl[(c4 + 3) * 65 + r] = v.w;
        }
        __syncthreads();
        int c = t >> 3, seg = t & 7;
        unsigned short tmp[8];
#pragma unroll
        for (int k = 0; k < 8; k++) tmp[k] = f2bf(tl[c * 65 + seg * 8 + k]);
        *(uint4*)(out + (size_t)(c0 + c) * R + r0 + seg * 8) = *(const uint4*)tmp;
        return;
    }
    // ---- gating: fp32 logits, exact top-2, softmax over top-2, fused h->bf16 cast (8 tokens/block) ----
    int wid = t >> 6, lane = t & 63;
    int n = (blockIdx.x - 2048) * 8 + wid;
    const float* hr = h + (size_t)n * DD;
    int d0 = lane * 8;
    float hv[8];
    *(float4*)(hv)     = *(const float4*)(hr + d0);
    *(float4*)(hv + 4) = *(const float4*)(hr + d0 + 4);
    unsigned short tmp[8];
#pragma unroll
    for (int j = 0; j < 8; j++) tmp[j] = f2bf(hv[j]);
    *(uint4*)(hb + (size_t)n * DD + d0) = *(const uint4*)tmp;

    float a0 = 0.f, a1 = 0.f, a2 = 0.f, a3 = 0.f;
#pragma unroll
    for (int j = 0; j < 8; j++) {
        float4 w = *(const float4*)(wg + (size_t)(d0 + j) * 4);
        a0 += hv[j] * w.x; a1 += hv[j] * w.y; a2 += hv[j] * w.z; a3 += hv[j] * w.w;
    }
#pragma unroll
    for (int off = 32; off; off >>= 1) {
        a0 += __shfl_xor(a0, off);
        a1 += __shfl_xor(a1, off);
        a2 += __shfl_xor(a2, off);
        a3 += __shfl_xor(a3, off);
    }
    if (lane == 0) {
        float v[4] = {a0, a1, a2, a3};
        int e0 = 0; float b = v[0];
#pragma unroll
        for (int e = 1; e < 4; e++) if (v[e] > b) { b = v[e]; e0 = e; }
        int e1 = -1; float b2 = -1e30f;
#pragma unroll
        for (int e = 0; e < 4; e++) if (e != e0 && v[e] > b2) { b2 = v[e]; e1 = e; }
        float x = expf(b2 - b);
        float s = 1.f + x;
        sel[2 * n] = e0; sel[2 * n + 1] = e1;
        gv[2 * n] = 1.f / s; gv[2 * n + 1] = x / s;
    }
}

// ---------------- single-block scan (1024 thr): shfl scans + LDS-staged coalesced outputs ----------------
// ctl: [8..11]=expert base, [12]=total, [13]=n256 tiles, [14]=n128 tiles
__global__ __launch_bounds__(1024) void k_scan(const int* __restrict__ sel,
                                               int* __restrict__ ctl, int* __restrict__ rtok,
                                               int* __restrict__ slotof,
                                               int* __restrict__ tiles, int* __restrict__ tiles2) {
    __shared__ int wtot[4][16];
    __shared__ int wbase[4][16];
    __shared__ int ebase[4];
    __shared__ int sL[16384];
    int t = threadIdx.x, w = t >> 6, lane = t & 63;
    int c[4] = {0, 0, 0, 0};
    int selloc[16];
    const int4* s4 = (const int4*)sel;
#pragma unroll
    for (int i = 0; i < 4; i++) {
        int4 v = s4[t * 4 + i];
        selloc[i * 4 + 0] = v.x; c[v.x]++;
        selloc[i * 4 + 1] = v.y; c[v.y]++;
        selloc[i * 4 + 2] = v.z; c[v.z]++;
        selloc[i * 4 + 3] = v.w; c[v.w]++;
    }
    int inc[4] = {c[0], c[1], c[2], c[3]};
#pragma unroll
    for (int off = 1; off < 64; off <<= 1) {
#pragma unroll
        for (int e = 0; e < 4; e++) {
            int v = __shfl_up(inc[e], off);
            if (lane >= off) inc[e] += v;
        }
    }
    if (lane == 63)
#pragma unroll
        for (int e = 0; e < 4; e++) wtot[e][w] = inc[e];
    __syncthreads();
    if (t == 0) {
        int o = 0, n256 = 0, n128 = 0;
#pragma unroll
        for (int e = 0; e < 4; e++) {
            int s = 0;
            for (int ww = 0; ww < 16; ww++) { wbase[e][ww] = s; s += wtot[e][ww]; }
            ebase[e] = o; ctl[8 + e] = o;
            for (int m0 = 0; m0 < s; m0 += 256) tiles[n256++] = (e << 16) | m0;
            for (int m0 = 0; m0 < s; m0 += 128) tiles2[n128++] = (e << 16) | m0;
            o += s;
        }
        ctl[12] = o; ctl[13] = n256; ctl[14] = n128;
    }
    __syncthreads();
    int pos[4];
#pragma unroll
    for (int e = 0; e < 4; e++) pos[e] = ebase[e] + wbase[e][w] + inc[e] - c[e];  // exclusive
    int slots[16];
#pragma unroll
    for (int i = 0; i < 16; i++) slots[i] = pos[selloc[i]]++;
#pragma unroll
    for (int i = 0; i < 4; i++) {
        int4 v; v.x = slots[4 * i]; v.y = slots[4 * i + 1]; v.z = slots[4 * i + 2]; v.w = slots[4 * i + 3];
        *(int4*)&slotof[t * 16 + i * 4] = v;
    }
#pragma unroll
    for (int i = 0; i < 16; i++) sL[slots[i]] = t * 16 + i;
    __syncthreads();
#pragma unroll
    for (int p = 0; p < 4; p++)
        *(int4*)&rtok[p * 4096 + t * 4] = *(const int4*)&sL[p * 4096 + t * 4];
}

// ---- grouped GEMM 1: 256x256, BK=64, 2-slot dbuf, 4-phase interleave, chunk-counted vmcnt ----
// Chunks/K-tile = 8x (64 rows x 64 k): issue order B0,B1|B2,B3|A0,A2|A1,A3 (2 per phase).
// P0 consumes {B*,A0,A2} = first-6-issued -> vmcnt(2); P2 consumes {A1,A3} -> vmcnt(4).
// 2-6 loads always in flight across barriers; drain-0 only at last tile's P2.
__global__ __launch_bounds__(512, 2) void k_ffn1(
    const unsigned short* __restrict__ hb, const unsigned short* __restrict__ w1t,
    const float* __restrict__ b1, const int* __restrict__ ctl, const int* __restrict__ tiles,
    const int* __restrict__ rtok, unsigned short* __restrict__ mid) {
    int flat = blockIdx.x;
    int c8 = flat & 7, q = flat >> 3;
    int nt = q & 7, mt = (q >> 3) * 8 + c8;
    if (mt >= ctl[13]) return;
    int tv = tiles[mt];
    int e = tv >> 16, m0 = tv & 0xFFFF;
    int base = ctl[8 + e];
    int cnt = ctl[9 + e] - base;
    int n0 = nt * 256;

    __shared__ unsigned short sm[2 * SLOT1];   // 128 KB dbuf; epilogue repack aliases
    __shared__ int toks[256];

    int t = threadIdx.x;
    if (t < 256) {
        int r = m0 + t; if (r >= cnt) r = cnt - 1;
        toks[t] = rtok[base + r] >> 1;
    }
    __syncthreads();

    const unsigned short* wB = w1t + (size_t)e * HH * DD;
    // chunk r covers rows [r*64, r*64+64); src granule pre-rotated by row (proven 0-conflict layout)
    const unsigned short* gA[4]; const unsigned short* gB[4];
    int lof[4];
#pragma unroll
    for (int r = 0; r < 4; r++) {
        int idx = r * 512 + t;
        int row = idx >> 3, sch = idx & 7;
        int cg = (sch - row) & 7;
        gA[r] = hb + (size_t)toks[row] * DD + cg * 8;
        gB[r] = wB + (size_t)(n0 + row) * DD + cg * 8;
        lof[r] = idx * 8;
    }

    int w = t >> 6, lane = t & 63;
    int wm = (w >> 2) * 128, wn = (w & 3) * 64;   // wave tile 128x64
    int lrow = lane & 15, quad = lane >> 4;

    floatx4 acc[8][4];
#pragma unroll
    for (int i = 0; i < 8; i++)
#pragma unroll
        for (int j = 0; j < 4; j++) acc[i][j] = (floatx4)0.f;

    // prologue: stage K-tile 0, in the canonical issue order
    gld_lds16(gB[0], sm + ASZ1 + lof[0]);
    gld_lds16(gB[1], sm + ASZ1 + lof[1]);
    gld_lds16(gB[2], sm + ASZ1 + lof[2]);
    gld_lds16(gB[3], sm + ASZ1 + lof[3]);
    gld_lds16(gA[0], sm + lof[0]);
    gld_lds16(gA[2], sm + lof[2]);
    gld_lds16(gA[1], sm + lof[1]);
    gld_lds16(gA[3], sm + lof[3]);

    const int NK = DD / 64;   // 8
    for (int tt = 0; tt < NK; tt++) {
        const unsigned short* SA = sm + (tt & 1) * SLOT1;
        const unsigned short* SB = SA + ASZ1;
        unsigned short* sb = sm + ((tt + 1) & 1) * SLOT1;
        int k1 = (tt + 1) * 64;
        bool more = (tt + 1 < NK);
        short8 af[4][2], bf[4][2];

        // ---------- P0: quadrant rows[wm..wm+64) x cols[wn..wn+32) ----------
        asm volatile("s_waitcnt vmcnt(2)" ::: "memory");   // tile tt's B*,A0,A2 landed
        __builtin_amdgcn_s_barrier();
        asm volatile("" ::: "memory");
#pragma unroll
        for (int i = 0; i < 4; i++)
#pragma unroll
            for (int ks = 0; ks < 2; ks++) {
                int row = wm + 16 * i + lrow;
                af[i][ks] = *(const short8*)&SA[row * 64 + (((ks << 2) + quad + row) & 7) * 8];
            }
#pragma unroll
        for (int j = 0; j < 2; j++)
#pragma unroll
            for (int ks = 0; ks < 2; ks++) {
                int row = wn + 16 * j + lrow;
                bf[j][ks] = *(const short8*)&SB[row * 64 + (((ks << 2) + quad + row) & 7) * 8];
            }
        if (more) { gld_lds16(gB[0] + k1, sb + ASZ1 + lof[0]); gld_lds16(gB[1] + k1, sb + ASZ1 + lof[1]); }
        __builtin_amdgcn_s_setprio(1);
#pragma unroll
        for (int i = 0; i < 4; i++)
#pragma unroll
            for (int j = 0; j < 2; j++)
#pragma unroll
                for (int ks = 0; ks < 2; ks++)
                    acc[i][j] = __builtin_amdgcn_mfma_f32_16x16x32_bf16(af[i][ks], bf[j][ks], acc[i][j], 0, 0, 0);
        __builtin_amdgcn_s_setprio(0);
        asm volatile("" ::: "memory");

        // ---------- P1: rows[wm..wm+64) x cols[wn+32..wn+64) ----------
        __builtin_amdgcn_s_barrier();
        asm volatile("" ::: "memory");
#pragma unroll
        for (int j = 2; j < 4; j++)
#pragma unroll
            for (int ks = 0; ks < 2; ks++) {
                int row = wn + 16 * j + lrow;
                bf[j][ks] = *(const short8*)&SB[row * 64 + (((ks << 2) + quad + row) & 7) * 8];
            }
        if (more) { gld_lds16(gB[2] + k1, sb + ASZ1 + lof[2]); gld_lds16(gB[3] + k1, sb + ASZ1 + lof[3]); }
        __builtin_amdgcn_s_setprio(1);
#pragma unroll
        for (int i = 0; i < 4; i++)
#pragma unroll
            for (int j = 2; j < 4; j++)
#pragma unroll
                for (int ks = 0; ks < 2; ks++)
                    acc[i][j] = __builtin_amdgcn_mfma_f32_16x16x32_bf16(af[i][ks], bf[j][ks], acc[i][j], 0, 0, 0);
        __builtin_amdgcn_s_setprio(0);
        asm volatile("" ::: "memory");

        // ---------- P2: rows[wm+64..wm+128) x cols[wn..wn+32) ----------
        if (more) asm volatile("s_waitcnt vmcnt(4)" ::: "memory");   // tile tt's A1,A3 landed
        else      asm volatile("s_waitcnt vmcnt(0)" ::: "memory");
        __builtin_amdgcn_s_barrier();
        asm volatile("" ::: "memory");
#pragma unroll
        for (int i = 0; i < 4; i++)
#pragma unroll
            for (int ks = 0; ks < 2; ks++) {
                int row = wm + 64 + 16 * i + lrow;
                af[i][ks] = *(const short8*)&SA[row * 64 + (((ks << 2) + quad + row) & 7) * 8];
            }
        if (more) { gld_lds16(gA[0] + k1, sb + lof[0]); gld_lds16(gA[2] + k1, sb + lof[2]); }
        __builtin_amdgcn_s_setprio(1);
#pragma unroll
        for (int i = 0; i < 4; i++)
#pragma unroll
            for (int j = 0; j < 2; j++)
#pragma unroll
                for (int ks = 0; ks < 2; ks++)
                    acc[4 + i][j] = __builtin_amdgcn_mfma_f32_16x16x32_bf16(af[i][ks], bf[j][ks], acc[4 + i][j], 0, 0, 0);
        __builtin_amdgcn_s_setprio(0);
        asm volatile("" ::: "memory");

        // ---------- P3: rows[wm+64..wm+128) x cols[wn+32..wn+64) ----------
        __builtin_amdgcn_s_barrier();
        asm volatile("" ::: "memory");
        if (more) { gld_lds16(gA[1] + k1, sb + lof[1]); gld_lds16(gA[3] + k1, sb + lof[3]); }
        __builtin_amdgcn_s_setprio(1);
#pragma unroll
        for (int i = 0; i < 4; i++)
#pragma unroll
            for (int j = 2; j < 4; j++)
#pragma unroll
                for (int ks = 0; ks < 2; ks++)
                    acc[4 + i][j] = __builtin_amdgcn_mfma_f32_16x16x32_bf16(af[i][ks], bf[j][ks], acc[4 + i][j], 0, 0, 0);
        __builtin_amdgcn_s_setprio(0);
        asm volatile("" ::: "memory");
    }
    __syncthreads();   // full drain before repack aliases the slots

    // epilogue: bias + relu -> repack (two 128-row passes) -> coalesced 128B stores
    float bias[4];
#pragma unroll
    for (int j = 0; j < 4; j++) bias[j] = b1[e * HH + n0 + wn + 16 * j + lrow];
#pragma unroll
    for (int half = 0; half < 2; half++) {
        if ((w >> 2) == half) {
#pragma unroll
            for (int j = 0; j < 4; j++) {
                int col = wn + 16 * j + lrow;
#pragma unroll
                for (int i = 0; i < 8; i++) {
#pragma unroll
                    for (int r = 0; r < 4; r++) {
                        int lm = 16 * i + quad * 4 + r;    // local row within half
                        float v = acc[i][j][r] + bias[j];
                        v = v > 0.f ? v : 0.f;
                        sm[lm * RP1 + col] = f2bf(v);
                    }
                }
            }
        }
        __syncthreads();
        int row = t >> 2, seg = t & 3;    // 128 rows x 4 segs of 128B
        int grow = half * 128 + row;
        if (m0 + grow < cnt) {
            unsigned short* dst = mid + (size_t)(base + m0 + grow) * HH + n0 + seg * 64;
            const unsigned short* src = sm + row * RP1 + seg * 64;
#pragma unroll
            for (int k = 0; k < 8; k++)
                *(uint4*)(dst + k * 8) = *(const uint4*)(src + k * 8);
        }
        __syncthreads();
    }
}

// ---- grouped GEMM 2: 128x128, BK=64, 2-slot dbuf (2 blk/CU), pre-issue + vmcnt(2) ----
// Chunks/K-tile = 4x (64 rows): issue order A0,A1 (pre-entry, after prev exit barrier) | B0,B1 (mid-phase).
// Entry wait vmcnt(2) drains tile tt's 4 chunks; 2-4 loads in flight across barriers.
__global__ __launch_bounds__(512, 2) void k_ffn2(
    const unsigned short* __restrict__ mid, const unsigned short* __restrict__ w2t,
    const float* __restrict__ b2, const int* __restrict__ ctl, const int* __restrict__ tiles2,
    const float* __restrict__ gv, const int* __restrict__ rtok, unsigned short* __restrict__ ybuf) {
    int flat = blockIdx.x;
    int c8 = flat & 7, q = flat >> 3;
    int nt = q & 3, mt = (q >> 2) * 8 + c8;
    if (mt >= ctl[14]) return;
    int tv = tiles2[mt];
    int e = tv >> 16, m0 = tv & 0xFFFF;
    int base = ctl[8 + e];
    int cnt = ctl[9 + e] - base;
    int n0 = nt * 128;

    __shared__ unsigned short sm[2 * SLOT2];   // 64 KB dbuf; epilogue repack aliases
    __shared__ float gts[128];

    int t = threadIdx.x;
    if (t < 128) {
        int r = m0 + t; if (r >= cnt) r = cnt - 1;
        gts[t] = gv[rtok[base + r]];
    }
    __syncthreads();

    const unsigned short* wB = w2t + (size_t)e * DD * HH;
    const unsigned short* gA[2]; const unsigned short* gB[2];
    int lofA[2], lofB[2];
#pragma unroll
    for (int r = 0; r < 2; r++) {
        int idx = r * 512 + t;
        int row = idx >> 3, sch = idx & 7;
        int cg = (sch - row) & 7;
        int ra = m0 + row; if (ra >= cnt) ra = cnt - 1;
        gA[r] = mid + (size_t)(base + ra) * HH + cg * 8;
        lofA[r] = idx * 8;
        gB[r] = wB + (size_t)(n0 + row) * HH + cg * 8;
        lofB[r] = ASZ2 + idx * 8;
    }

    int w = t >> 6, lane = t & 63;
    int wm = (w & 3) * 32, wn = (w >> 2) * 64;   // wave tile 32x64
    int lrow = lane & 15, quad = lane >> 4;

    floatx4 acc[2][4];
#pragma unroll
    for (int i = 0; i < 2; i++)
#pragma unroll
        for (int j = 0; j < 4; j++) acc[i][j] = (floatx4)0.f;

    // prologue: stage K-tile 0 (issue order A0,A1,B0,B1)
    gld_lds16(gA[0], sm + lofA[0]);
    gld_lds16(gA[1], sm + lofA[1]);
    gld_lds16(gB[0], sm + lofB[0]);
    gld_lds16(gB[1], sm + lofB[1]);

    const int NK = HH / 64;   // 32
    for (int tt = 0; tt < NK; tt++) {
        const unsigned short* SA = sm + (tt & 1) * SLOT2;
        const unsigned short* SB = SA + ASZ2;
        unsigned short* sb = sm + ((tt + 1) & 1) * SLOT2;
        int k1 = (tt + 1) * 64;
        bool more = (tt + 1 < NK);

        // pre-entry issue of next tile's A-chunks (safe: prev exit barrier retired 1-p's readers)
        if (more) {
            gld_lds16(gA[0] + k1, sb + lofA[0]);
            gld_lds16(gA[1] + k1, sb + lofA[1]);
            asm volatile("s_waitcnt vmcnt(2)" ::: "memory");   // tile tt's 4 chunks landed
        } else {
            asm volatile("s_waitcnt vmcnt(0)" ::: "memory");
        }
        __builtin_amdgcn_s_barrier();
        asm volatile("" ::: "memory");

        short8 af[2][2], bfa[2][2], bfb[2][2];
#pragma unroll
        for (int i = 0; i < 2; i++)
#pragma unroll
            for (int ks = 0; ks < 2; ks++) {
                int row = wm + 16 * i + lrow;
                af[i][ks] = *(const short8*)&SA[row * 64 + (((ks << 2) + quad + row) & 7) * 8];
            }
#pragma unroll
        for (int j = 0; j < 2; j++)
#pragma unroll
            for (int ks = 0; ks < 2; ks++) {
                int row = wn + 16 * j + lrow;
                bfa[j][ks] = *(const short8*)&SB[row * 64 + (((ks << 2) + quad + row) & 7) * 8];
            }
        if (more) {
            gld_lds16(gB[0] + k1, sb + lofB[0]);
            gld_lds16(gB[1] + k1, sb + lofB[1]);
        }
        __builtin_amdgcn_s_setprio(1);
#pragma unroll
        for (int i = 0; i < 2; i++)
#pragma unroll
            for (int j = 0; j < 2; j++)
#pragma unroll
                for (int ks = 0; ks < 2; ks++)
                    acc[i][j] = __builtin_amdgcn_mfma_f32_16x16x32_bf16(af[i][ks], bfa[j][ks], acc[i][j], 0, 0, 0);
        __builtin_amdgcn_s_setprio(0);
#pragma unroll
        for (int j = 0; j < 2; j++)
#pragma unroll
            for (int ks = 0; ks < 2; ks++) {
                int row = wn + 32 + 16 * j + lrow;
                bfb[j][ks] = *(const short8*)&SB[row * 64 + (((ks << 2) + quad + row) & 7) * 8];
            }
        __builtin_amdgcn_s_setprio(1);
#pragma unroll
        for (int i = 0; i < 2; i++)
#pragma unroll
            for (int j = 0; j < 2; j++)
#pragma unroll
                for (int ks = 0; ks < 2; ks++)
                    acc[i][2 + j] = __builtin_amdgcn_mfma_f32_16x16x32_bf16(af[i][ks], bfb[j][ks], acc[i][2 + j], 0, 0, 0);
        __builtin_amdgcn_s_setprio(0);
        asm volatile("" ::: "memory");
        __builtin_amdgcn_s_barrier();   // exit barrier: all reads of buf p retired
        asm volatile("" ::: "memory");
    }
    __syncthreads();

    // epilogue: bias + gate-scale -> repack (128 x RP2) -> coalesced stores
    float b2v[4];
#pragma unroll
    for (int j = 0; j < 4; j++) b2v[j] = b2[e * DD + n0 + wn + 16 * j + lrow];
#pragma unroll
    for (int j = 0; j < 4; j++) {
        int col = wn + 16 * j + lrow;
#pragma unroll
        for (int i = 0; i < 2; i++) {
#pragma unroll
            for (int r = 0; r < 4; r++) {
                int m = wm + 16 * i + quad * 4 + r;
                float v = (acc[i][j][r] + b2v[j]) * gts[m];
                sm[m * RP2 + col] = f2bf(v);
            }
        }
    }
    __syncthreads();
    {
        int row = t >> 2, q4 = t & 3;   // 128 rows x 4 chunks of 32 elems
        if (m0 + row < cnt) {
            unsigned short* dst = ybuf + (size_t)(base + m0 + row) * DD + n0 + q4 * 32;
            const unsigned short* src = sm + row * RP2 + q4 * 32;
#pragma unroll
            for (int it = 0; it < 4; it++)
                *(uint4*)(dst + it * 8) = *(const uint4*)(src + it * 8);
        }
    }
}

// ---------------- combine (512 thr, 4 tokens/block): out[n] = ybuf[slot(n,0)] + ybuf[slot(n,1)] ----------------
__global__ __launch_bounds__(512) void k_combine(const unsigned short* __restrict__ ybuf,
                                                 const int* __restrict__ slotof,
                                                 float* __restrict__ out) {
    int n = blockIdx.x * 4 + (threadIdx.x >> 7);
    int c = (threadIdx.x & 127) * 4;
    int sA = slotof[2 * n], sB = slotof[2 * n + 1];
    ushort4 a = *(const ushort4*)(ybuf + (size_t)sA * DD + c);
    ushort4 b = *(const ushort4*)(ybuf + (size_t)sB * DD + c);
    float4 o;
    o.x = bf2f(a.x) + bf2f(b.x);
    o.y = bf2f(a.y) + bf2f(b.y);
    o.z = bf2f(a.z) + bf2f(b.z);
    o.w = bf2f(a.w) + bf2f(b.w);
    *(float4*)(out + (size_t)n * DD + c) = o;
}

extern "C" void kernel_launch(void* const* d_in, const int* in_sizes, int n_in,
                              void* d_out, int out_size, void* d_ws, size_t ws_size,
                              hipStream_t stream) {
    const float* h  = (const float*)d_in[0];
    const float* wg = (const float*)d_in[1];
    const float* w1 = (const float*)d_in[2];
    const float* b1 = (const float*)d_in[3];
    const float* w2 = (const float*)d_in[4];
    const float* b2 = (const float*)d_in[5];
    float* out = (float*)d_out;

    char* ws = (char*)d_ws;
    size_t off = 0;
    auto alloc = [&](size_t bytes) -> void* {
        void* p = ws + off;
        off += (bytes + 255) & ~(size_t)255;
        return p;
    };
    unsigned short* hb  = (unsigned short*)alloc((size_t)NT * DD * 2);        // dead after ffn1
    unsigned short* w1t = (unsigned short*)alloc((size_t)NE * HH * DD * 2);   // dead after ffn1
    unsigned short* w2t = (unsigned short*)alloc((size_t)NE * DD * HH * 2);
    int*   sel    = (int*)alloc((size_t)NT * 2 * 4);
    float* gv     = (float*)alloc((size_t)NT * 2 * 4);
    int*   ctl    = (int*)alloc(256);
    int*   tiles  = (int*)alloc(1024);
    int*   tiles2 = (int*)alloc(2048);
    int*   rtok   = (int*)alloc((size_t)NT * 2 * 4);
    int*   slotof = (int*)alloc((size_t)NT * 2 * 4);
    unsigned short* mid = (unsigned short*)alloc((size_t)NT * 2 * HH * 2);
    // ybuf [NT*2][DD] bf16 (16.7 MB) aliases hb+w1t (16.7 MB), both dead before ffn2 runs
    unsigned short* ybuf = (unsigned short*)ws;

    k_prep<<<dim3(2048 + NT / 8), 512, 0, stream>>>(w1, w1t, w2, w2t, h, wg, sel, gv, hb);
    k_scan<<<1, 1024, 0, stream>>>(sel, ctl, rtok, slotof, tiles, tiles2);
    k_ffn1<<<dim3(FFN1_GRID), 512, 0, stream>>>(hb, w1t, b1, ctl, tiles, rtok, mid);
    k_ffn2<<<dim3(FFN2_GRID), 512, 0, stream>>>(mid, w2t, b2, ctl, tiles2, gv, rtok, ybuf);
    k_combine<<<dim3(NT / 4), 512, 0, stream>>>(ybuf, slotof, out);
}

// Round 5
// 234.893 us; speedup vs baseline: 1.3067x; 1.0356x over previous
//
#include <hip/hip_runtime.h>
#include <hip/hip_bf16.h>
#include <cstdint>
#include <cstddef>

// Problem constants
#define NT 8192
#define DD 512
#define HH 2048
#define NE 4
// ffn1: BM=160,BN=256,BK=64, 2-slot dbuf (104 KB, 1 blk/CU), ~832 blocks -> 4 rounds (was 3 rounds of 536)
#define SLOT1 26624    // shorts: A 160x64 (10240) + B 256x64 (16384)
#define ASZ1  10240
// ffn2: BM=160,BN=128,BK=64, 2-slot dbuf (74 KB, 2 blk/CU), ~416 blocks -> ALL co-resident (1 round)
#define SLOT2 18432    // shorts: A 160x64 (10240) + B 128x64 (8192)
#define ASZ2  10240
#define RP1 264        // ffn1 repack row stride (shorts)
#define RP2 136        // ffn2 repack row stride (shorts)
#define FFN1_GRID 896  // 14 mt-groups x 8 xcd x 8 n-tiles (covers <=106 m-tiles of 160)
#define FFN2_GRID 448  // 14 mt-groups x 8 xcd x 4 n-tiles

typedef short short8 __attribute__((ext_vector_type(8)));
typedef float floatx4 __attribute__((ext_vector_type(4)));

static __device__ __forceinline__ unsigned short f2bf(float f) {
    union { float f; uint32_t u; } v; v.f = f;
    uint32_t u = v.u;
    u += 0x7FFFu + ((u >> 16) & 1u);   // round-to-nearest-even
    return (unsigned short)(u >> 16);
}
static __device__ __forceinline__ float bf2f(unsigned short u) {
    union { uint32_t u; float f; } v; v.u = ((uint32_t)u) << 16; return v.f;
}

// async global->LDS, 16B per lane. LDS dest = wave-uniform base + lane*16 (addresses below are lane-linear).
static __device__ __forceinline__ void gld_lds16(const unsigned short* g, unsigned short* l) {
    __builtin_amdgcn_global_load_lds(
        (const __attribute__((address_space(1))) void*)g,
        (__attribute__((address_space(3))) void*)l, 16, 0, 0);
}

// ------------- merged prep (512 thr): weight transpose+cast (blocks 0..2047) + gate (2048..) -------------
__global__ __launch_bounds__(512) void k_prep(
    const float* __restrict__ w1, unsigned short* __restrict__ w1t,
    const float* __restrict__ w2, unsigned short* __restrict__ w2t,
    const float* __restrict__ h, const float* __restrict__ wg,
    int* __restrict__ sel, float* __restrict__ gv, unsigned short* __restrict__ hb) {
    int t = threadIdx.x;
    if (blockIdx.x < 2048) {
        int z = blockIdx.x >> 8;            // 256 blocks per expert-matrix
        int rem = blockIdx.x & 255;
        const float* in; unsigned short* out; int R, C, by, bx;
        if (z < 4) {
            in = w1 + (size_t)z * DD * HH; out = w1t + (size_t)z * DD * HH;
            R = DD; C = HH; by = rem >> 5; bx = rem & 31;      // 8 x 32 tiles
        } else {
            in = w2 + (size_t)(z - 4) * HH * DD; out = w2t + (size_t)(z - 4) * HH * DD;
            R = HH; C = DD; by = rem >> 3; bx = rem & 7;       // 32 x 8 tiles
        }
        int r0 = by * 64, c0 = bx * 64;
        __shared__ float tl[64 * 65];       // tl[c*65 + r] (col-major, S=65 -> conflict-free)
        int rr = t >> 4, c4 = (t & 15) * 4;
#pragma unroll
        for (int p = 0; p < 2; p++) {
            int r = rr + p * 32;
            float4 v = *(const float4*)(in + (size_t)(r0 + r) * C + c0 + c4);
            tl[(c4 + 0) * 65 + r] = v.x;
            tl[(c4 + 1) * 65 + r] = v.y;
            tl[(c4 + 2) * 65 + r] = v.z;
            tl[(c4 + 3) * 65 + r] = v.w;
        }
        __syncthreads();
        int c = t >> 3, seg = t & 7;
        unsigned short tmp[8];
#pragma unroll
        for (int k = 0; k < 8; k++) tmp[k] = f2bf(tl[c * 65 + seg * 8 + k]);
        *(uint4*)(out + (size_t)(c0 + c) * R + r0 + seg * 8) = *(const uint4*)tmp;
        return;
    }
    // ---- gating: fp32 logits, exact top-2, softmax over top-2, fused h->bf16 cast (8 tokens/block) ----
    int wid = t >> 6, lane = t & 63;
    int n = (blockIdx.x - 2048) * 8 + wid;
    const float* hr = h + (size_t)n * DD;
    int d0 = lane * 8;
    float hv[8];
    *(float4*)(hv)     = *(const float4*)(hr + d0);
    *(float4*)(hv + 4) = *(const float4*)(hr + d0 + 4);
    unsigned short tmp[8];
#pragma unroll
    for (int j = 0; j < 8; j++) tmp[j] = f2bf(hv[j]);
    *(uint4*)(hb + (size_t)n * DD + d0) = *(const uint4*)tmp;

    float a0 = 0.f, a1 = 0.f, a2 = 0.f, a3 = 0.f;
#pragma unroll
    for (int j = 0; j < 8; j++) {
        float4 w = *(const float4*)(wg + (size_t)(d0 + j) * 4);
        a0 += hv[j] * w.x; a1 += hv[j] * w.y; a2 += hv[j] * w.z; a3 += hv[j] * w.w;
    }
#pragma unroll
    for (int off = 32; off; off >>= 1) {
        a0 += __shfl_xor(a0, off);
        a1 += __shfl_xor(a1, off);
        a2 += __shfl_xor(a2, off);
        a3 += __shfl_xor(a3, off);
    }
    if (lane == 0) {
        float v[4] = {a0, a1, a2, a3};
        int e0 = 0; float b = v[0];
#pragma unroll
        for (int e = 1; e < 4; e++) if (v[e] > b) { b = v[e]; e0 = e; }
        int e1 = -1; float b2 = -1e30f;
#pragma unroll
        for (int e = 0; e < 4; e++) if (e != e0 && v[e] > b2) { b2 = v[e]; e1 = e; }
        float x = expf(b2 - b);
        float s = 1.f + x;
        sel[2 * n] = e0; sel[2 * n + 1] = e1;
        gv[2 * n] = 1.f / s; gv[2 * n + 1] = x / s;
    }
}

// ---------------- single-block scan (1024 thr): shfl scans + LDS-staged coalesced outputs ----------------
// ctl: [8..11]=expert base, [12]=total, [13]=n160 tiles
__global__ __launch_bounds__(1024) void k_scan(const int* __restrict__ sel,
                                               int* __restrict__ ctl, int* __restrict__ rtok,
                                               int* __restrict__ slotof,
                                               int* __restrict__ tiles) {
    __shared__ int wtot[4][16];
    __shared__ int wbase[4][16];
    __shared__ int ebase[4];
    __shared__ int sL[16384];
    int t = threadIdx.x, w = t >> 6, lane = t & 63;
    int c[4] = {0, 0, 0, 0};
    int selloc[16];
    const int4* s4 = (const int4*)sel;
#pragma unroll
    for (int i = 0; i < 4; i++) {
        int4 v = s4[t * 4 + i];
        selloc[i * 4 + 0] = v.x; c[v.x]++;
        selloc[i * 4 + 1] = v.y; c[v.y]++;
        selloc[i * 4 + 2] = v.z; c[v.z]++;
        selloc[i * 4 + 3] = v.w; c[v.w]++;
    }
    int inc[4] = {c[0], c[1], c[2], c[3]};
#pragma unroll
    for (int off = 1; off < 64; off <<= 1) {
#pragma unroll
        for (int e = 0; e < 4; e++) {
            int v = __shfl_up(inc[e], off);
            if (lane >= off) inc[e] += v;
        }
    }
    if (lane == 63)
#pragma unroll
        for (int e = 0; e < 4; e++) wtot[e][w] = inc[e];
    __syncthreads();
    if (t == 0) {
        int o = 0, ntl = 0;
#pragma unroll
        for (int e = 0; e < 4; e++) {
            int s = 0;
            for (int ww = 0; ww < 16; ww++) { wbase[e][ww] = s; s += wtot[e][ww]; }
            ebase[e] = o; ctl[8 + e] = o;
            for (int m0 = 0; m0 < s; m0 += 160) tiles[ntl++] = (e << 16) | m0;
            o += s;
        }
        ctl[12] = o; ctl[13] = ntl;
    }
    __syncthreads();
    int pos[4];
#pragma unroll
    for (int e = 0; e < 4; e++) pos[e] = ebase[e] + wbase[e][w] + inc[e] - c[e];  // exclusive
    int slots[16];
#pragma unroll
    for (int i = 0; i < 16; i++) slots[i] = pos[selloc[i]]++;
#pragma unroll
    for (int i = 0; i < 4; i++) {
        int4 v; v.x = slots[4 * i]; v.y = slots[4 * i + 1]; v.z = slots[4 * i + 2]; v.w = slots[4 * i + 3];
        *(int4*)&slotof[t * 16 + i * 4] = v;
    }
#pragma unroll
    for (int i = 0; i < 16; i++) sL[slots[i]] = t * 16 + i;
    __syncthreads();
#pragma unroll
    for (int p = 0; p < 4; p++)
        *(int4*)&rtok[p * 4096 + t * 4] = *(const int4*)&sL[p * 4096 + t * 4];
}

// ---- grouped GEMM 1: 160x256, BK=64, 2-slot dbuf, pre-issue A + vmcnt(3) counted waits ----
// mid = relu(gather(h) @ w1[e] + b1[e]); 8 waves of 80x64 (2Mx4N)
// Per K-tile: 7 chunks/thread (3 A incl. 1 dup-pad + 4 B). FIFO order: A(t+1) pre-entry, B(t+1) mid-phase.
__global__ __launch_bounds__(512, 2) void k_ffn1(
    const unsigned short* __restrict__ hb, const unsigned short* __restrict__ w1t,
    const float* __restrict__ b1, const int* __restrict__ ctl, const int* __restrict__ tiles,
    const int* __restrict__ rtok, unsigned short* __restrict__ mid) {
    int flat = blockIdx.x;
    int c8 = flat & 7, q = flat >> 3;
    int nt = q & 7, mt = (q >> 3) * 8 + c8;
    if (mt >= ctl[13]) return;
    int tv = tiles[mt];
    int e = tv >> 16, m0 = tv & 0xFFFF;
    int base = ctl[8 + e];
    int cnt = ctl[9 + e] - base;
    int n0 = nt * 256;

    __shared__ unsigned short sm[2 * SLOT1];   // 104 KB dbuf; epilogue repack (160 x RP1) aliases
    __shared__ int toks[160];

    int t = threadIdx.x;
    if (t < 160) {
        int r = m0 + t; if (r >= cnt) r = cnt - 1;
        toks[t] = rtok[base + r] >> 1;
    }
    __syncthreads();

    const unsigned short* wB = w1t + (size_t)e * HH * DD;
    // A: 160 rows x 8 granules = 1280 lane-slots = 2.5 rounds -> 3 rounds; threads t>=256 in round 2
    // re-issue their own round-1 load (same src+dst, benign) so per-thread issue counts stay uniform.
    int idxA[3]; idxA[0] = t; idxA[1] = 512 + t; idxA[2] = (t < 256) ? (1024 + t) : (512 + t);
    const unsigned short* gA[3]; int lofA[3];
#pragma unroll
    for (int r = 0; r < 3; r++) {
        int row = idxA[r] >> 3, sch = idxA[r] & 7;
        int cg = (sch - row) & 7;
        gA[r] = hb + (size_t)toks[row] * DD + cg * 8;
        lofA[r] = idxA[r] * 8;
    }
    const unsigned short* gB[4]; int lofB[4];
#pragma unroll
    for (int r = 0; r < 4; r++) {
        int idx = r * 512 + t;
        int row = idx >> 3, sch = idx & 7;
        int cg = (sch - row) & 7;
        gB[r] = wB + (size_t)(n0 + row) * DD + cg * 8;
        lofB[r] = ASZ1 + idx * 8;
    }

    int w = t >> 6, lane = t & 63;
    int wm = (w >> 2) * 80, wn = (w & 3) * 64;   // wave tile 80x64
    int lrow = lane & 15, quad = lane >> 4;

    floatx4 acc[5][4];
#pragma unroll
    for (int i = 0; i < 5; i++)
#pragma unroll
        for (int j = 0; j < 4; j++) acc[i][j] = (floatx4)0.f;

    // prologue: stage K-tile 0 (A then B, FIFO-monotone)
#pragma unroll
    for (int r = 0; r < 3; r++) gld_lds16(gA[r], sm + lofA[r]);
#pragma unroll
    for (int r = 0; r < 4; r++) gld_lds16(gB[r], sm + lofB[r]);

    const int NK = DD / 64;   // 8
    for (int tt = 0; tt < NK; tt++) {
        const unsigned short* SA = sm + (tt & 1) * SLOT1;
        const unsigned short* SB = SA + ASZ1;
        unsigned short* sb = sm + ((tt + 1) & 1) * SLOT1;
        int k1 = (tt + 1) * 64;
        bool more = (tt + 1 < NK);

        // pre-entry: issue next tile's A (3), then counted wait: tile tt's 7 chunks are the only
        // older ops -> vmcnt(3) guarantees they landed while the 3 new A stay in flight.
        if (more) {
#pragma unroll
            for (int r = 0; r < 3; r++) gld_lds16(gA[r] + k1, sb + lofA[r]);
            asm volatile("s_waitcnt vmcnt(3)" ::: "memory");
        } else {
            asm volatile("s_waitcnt vmcnt(0)" ::: "memory");
        }
        __builtin_amdgcn_s_barrier();
        asm volatile("" ::: "memory");

        short8 af[5][2], bf[2][2];
#pragma unroll
        for (int i = 0; i < 5; i++)
#pragma unroll
            for (int ks = 0; ks < 2; ks++) {
                int row = wm + 16 * i + lrow;
                af[i][ks] = *(const short8*)&SA[row * 64 + (((ks << 2) + quad + row) & 7) * 8];
            }
#pragma unroll
        for (int j = 0; j < 2; j++)
#pragma unroll
            for (int ks = 0; ks < 2; ks++) {
                int row = wn + 16 * j + lrow;
                bf[j][ks] = *(const short8*)&SB[row * 64 + (((ks << 2) + quad + row) & 7) * 8];
            }
        if (more) { gld_lds16(gB[0] + k1, sb + lofB[0]); gld_lds16(gB[1] + k1, sb + lofB[1]); }
        __builtin_amdgcn_s_setprio(1);
#pragma unroll
        for (int i = 0; i < 5; i++)
#pragma unroll
            for (int j = 0; j < 2; j++)
#pragma unroll
                for (int ks = 0; ks < 2; ks++)
                    acc[i][j] = __builtin_amdgcn_mfma_f32_16x16x32_bf16(af[i][ks], bf[j][ks], acc[i][j], 0, 0, 0);
        __builtin_amdgcn_s_setprio(0);
#pragma unroll
        for (int j = 0; j < 2; j++)
#pragma unroll
            for (int ks = 0; ks < 2; ks++) {
                int row = wn + 32 + 16 * j + lrow;
                bf[j][ks] = *(const short8*)&SB[row * 64 + (((ks << 2) + quad + row) & 7) * 8];
            }
        if (more) { gld_lds16(gB[2] + k1, sb + lofB[2]); gld_lds16(gB[3] + k1, sb + lofB[3]); }
        __builtin_amdgcn_s_setprio(1);
#pragma unroll
        for (int i = 0; i < 5; i++)
#pragma unroll
            for (int j = 0; j < 2; j++)
#pragma unroll
                for (int ks = 0; ks < 2; ks++)
                    acc[i][2 + j] = __builtin_amdgcn_mfma_f32_16x16x32_bf16(af[i][ks], bf[j][ks], acc[i][2 + j], 0, 0, 0);
        __builtin_amdgcn_s_setprio(0);
        asm volatile("" ::: "memory");
        __builtin_amdgcn_s_barrier();   // exit: all reads of slot (tt&1) retired
        asm volatile("" ::: "memory");
    }
    __syncthreads();   // before repack aliases the slots

    // epilogue: bias + relu -> repack (160 x RP1, single pass) -> coalesced 128B stores
    float bias[4];
#pragma unroll
    for (int j = 0; j < 4; j++) bias[j] = b1[e * HH + n0 + wn + 16 * j + lrow];
#pragma unroll
    for (int j = 0; j < 4; j++) {
        int col = wn + 16 * j + lrow;
#pragma unroll
        for (int i = 0; i < 5; i++) {
#pragma unroll
            for (int r = 0; r < 4; r++) {
                int m = wm + 16 * i + quad * 4 + r;
                float v = acc[i][j][r] + bias[j];
                v = v > 0.f ? v : 0.f;
                sm[m * RP1 + col] = f2bf(v);
            }
        }
    }
    __syncthreads();
#pragma unroll
    for (int p = 0; p < 2; p++) {
        int row = p * 128 + (t >> 2), seg = t & 3;   // rows 0..159 x 4 segs of 128B
        if (row < 160 && m0 + row < cnt) {
            unsigned short* dst = mid + (size_t)(base + m0 + row) * HH + n0 + seg * 64;
            const unsigned short* src = sm + row * RP1 + seg * 64;
#pragma unroll
            for (int k = 0; k < 8; k++)
                *(uint4*)(dst + k * 8) = *(const uint4*)(src + k * 8);
        }
    }
}

// ---- grouped GEMM 2: 160x128, BK=64, 2-slot dbuf (74 KB -> 2 blk/CU, ~416 blocks ALL resident) ----
// ybuf[slot] = gate * (mid @ w2[e] + b2[e]); 8 waves of 80x32; 5 chunks/thread (3 A dup-pad + 2 B)
__global__ __launch_bounds__(512, 4) void k_ffn2(
    const unsigned short* __restrict__ mid, const unsigned short* __restrict__ w2t,
    const float* __restrict__ b2, const int* __restrict__ ctl, const int* __restrict__ tiles,
    const float* __restrict__ gv, const int* __restrict__ rtok, unsigned short* __restrict__ ybuf) {
    int flat = blockIdx.x;
    int c8 = flat & 7, q = flat >> 3;
    int nt = q & 3, mt = (q >> 2) * 8 + c8;
    if (mt >= ctl[13]) return;
    int tv = tiles[mt];
    int e = tv >> 16, m0 = tv & 0xFFFF;
    int base = ctl[8 + e];
    int cnt = ctl[9 + e] - base;
    int n0 = nt * 128;

    __shared__ unsigned short sm[2 * SLOT2];   // 72 KB dbuf; epilogue repack (160 x RP2) aliases
    __shared__ float gts[160];

    int t = threadIdx.x;
    if (t < 160) {
        int r = m0 + t; if (r >= cnt) r = cnt - 1;
        gts[t] = gv[rtok[base + r]];
    }
    __syncthreads();

    const unsigned short* wB = w2t + (size_t)e * DD * HH;
    int idxA[3]; idxA[0] = t; idxA[1] = 512 + t; idxA[2] = (t < 256) ? (1024 + t) : (512 + t);
    const unsigned short* gA[3]; int lofA[3];
#pragma unroll
    for (int r = 0; r < 3; r++) {
        int row = idxA[r] >> 3, sch = idxA[r] & 7;
        int cg = (sch - row) & 7;
        int ra = m0 + row; if (ra >= cnt) ra = cnt - 1;
        gA[r] = mid + (size_t)(base + ra) * HH + cg * 8;
        lofA[r] = idxA[r] * 8;
    }
    const unsigned short* gB[2]; int lofB[2];
#pragma unroll
    for (int r = 0; r < 2; r++) {
        int idx = r * 512 + t;
        int row = idx >> 3, sch = idx & 7;
        int cg = (sch - row) & 7;
        gB[r] = wB + (size_t)(n0 + row) * HH + cg * 8;
        lofB[r] = ASZ2 + idx * 8;
    }

    int w = t >> 6, lane = t & 63;
    int wm = (w >> 2) * 80, wn = (w & 3) * 32;   // wave tile 80x32
    int lrow = lane & 15, quad = lane >> 4;

    floatx4 acc[5][2];
#pragma unroll
    for (int i = 0; i < 5; i++)
#pragma unroll
        for (int j = 0; j < 2; j++) acc[i][j] = (floatx4)0.f;

    // prologue: stage K-tile 0 (A then B)
#pragma unroll
    for (int r = 0; r < 3; r++) gld_lds16(gA[r], sm + lofA[r]);
#pragma unroll
    for (int r = 0; r < 2; r++) gld_lds16(gB[r], sm + lofB[r]);

    const int NK = HH / 64;   // 32
    for (int tt = 0; tt < NK; tt++) {
        const unsigned short* SA = sm + (tt & 1) * SLOT2;
        const unsigned short* SB = SA + ASZ2;
        unsigned short* sb = sm + ((tt + 1) & 1) * SLOT2;
        int k1 = (tt + 1) * 64;
        bool more = (tt + 1 < NK);

        if (more) {
#pragma unroll
            for (int r = 0; r < 3; r++) gld_lds16(gA[r] + k1, sb + lofA[r]);
            asm volatile("s_waitcnt vmcnt(3)" ::: "memory");   // tile tt's 5 chunks landed
        } else {
            asm volatile("s_waitcnt vmcnt(0)" ::: "memory");
        }
        __builtin_amdgcn_s_barrier();
        asm volatile("" ::: "memory");

        short8 af[5][2], bf[2][2];
#pragma unroll
        for (int i = 0; i < 5; i++)
#pragma unroll
            for (int ks = 0; ks < 2; ks++) {
                int row = wm + 16 * i + lrow;
                af[i][ks] = *(const short8*)&SA[row * 64 + (((ks << 2) + quad + row) & 7) * 8];
            }
#pragma unroll
        for (int j = 0; j < 2; j++)
#pragma unroll
            for (int ks = 0; ks < 2; ks++) {
                int row = wn + 16 * j + lrow;
                bf[j][ks] = *(const short8*)&SB[row * 64 + (((ks << 2) + quad + row) & 7) * 8];
            }
        if (more) { gld_lds16(gB[0] + k1, sb + lofB[0]); gld_lds16(gB[1] + k1, sb + lofB[1]); }
        __builtin_amdgcn_s_setprio(1);
#pragma unroll
        for (int i = 0; i < 5; i++)
#pragma unroll
            for (int j = 0; j < 2; j++)
#pragma unroll
                for (int ks = 0; ks < 2; ks++)
                    acc[i][j] = __builtin_amdgcn_mfma_f32_16x16x32_bf16(af[i][ks], bf[j][ks], acc[i][j], 0, 0, 0);
        __builtin_amdgcn_s_setprio(0);
        asm volatile("" ::: "memory");
        __builtin_amdgcn_s_barrier();
        asm volatile("" ::: "memory");
    }
    __syncthreads();

    // epilogue: bias + gate-scale -> repack (160 x RP2) -> coalesced stores
    float b2v[2];
#pragma unroll
    for (int j = 0; j < 2; j++) b2v[j] = b2[e * DD + n0 + wn + 16 * j + lrow];
#pragma unroll
    for (int j = 0; j < 2; j++) {
        int col = wn + 16 * j + lrow;
#pragma unroll
        for (int i = 0; i < 5; i++) {
#pragma unroll
            for (int r = 0; r < 4; r++) {
                int m = wm + 16 * i + quad * 4 + r;
                float v = (acc[i][j][r] + b2v[j]) * gts[m];
                sm[m * RP2 + col] = f2bf(v);
            }
        }
    }
    __syncthreads();
    {
        int row = t >> 1, half = t & 1;   // rows 0..159 x 2 segs of 128B (t < 320 active)
        if (row < 160 && m0 + row < cnt) {
            unsigned short* dst = ybuf + (size_t)(base + m0 + row) * DD + n0 + half * 64;
            const unsigned short* src = sm + row * RP2 + half * 64;
#pragma unroll
            for (int k = 0; k < 8; k++)
                *(uint4*)(dst + k * 8) = *(const uint4*)(src + k * 8);
        }
    }
}

// ---------------- combine (512 thr, 4 tokens/block): out[n] = ybuf[slot(n,0)] + ybuf[slot(n,1)] ----------------
__global__ __launch_bounds__(512) void k_combine(const unsigned short* __restrict__ ybuf,
                                                 const int* __restrict__ slotof,
                                                 float* __restrict__ out) {
    int n = blockIdx.x * 4 + (threadIdx.x >> 7);
    int c = (threadIdx.x & 127) * 4;
    int sA = slotof[2 * n], sB = slotof[2 * n + 1];
    ushort4 a = *(const ushort4*)(ybuf + (size_t)sA * DD + c);
    ushort4 b = *(const ushort4*)(ybuf + (size_t)sB * DD + c);
    float4 o;
    o.x = bf2f(a.x) + bf2f(b.x);
    o.y = bf2f(a.y) + bf2f(b.y);
    o.z = bf2f(a.z) + bf2f(b.z);
    o.w = bf2f(a.w) + bf2f(b.w);
    *(float4*)(out + (size_t)n * DD + c) = o;
}

extern "C" void kernel_launch(void* const* d_in, const int* in_sizes, int n_in,
                              void* d_out, int out_size, void* d_ws, size_t ws_size,
                              hipStream_t stream) {
    const float* h  = (const float*)d_in[0];
    const float* wg = (const float*)d_in[1];
    const float* w1 = (const float*)d_in[2];
    const float* b1 = (const float*)d_in[3];
    const float* w2 = (const float*)d_in[4];
    const float* b2 = (const float*)d_in[5];
    float* out = (float*)d_out;

    char* ws = (char*)d_ws;
    size_t off = 0;
    auto alloc = [&](size_t bytes) -> void* {
        void* p = ws + off;
        off += (bytes + 255) & ~(size_t)255;
        return p;
    };
    unsigned short* hb  = (unsigned short*)alloc((size_t)NT * DD * 2);        // dead after ffn1
    unsigned short* w1t = (unsigned short*)alloc((size_t)NE * HH * DD * 2);   // dead after ffn1
    unsigned short* w2t = (unsigned short*)alloc((size_t)NE * DD * HH * 2);
    int*   sel    = (int*)alloc((size_t)NT * 2 * 4);
    float* gv     = (float*)alloc((size_t)NT * 2 * 4);
    int*   ctl    = (int*)alloc(256);
    int*   tiles  = (int*)alloc(1024);
    int*   rtok   = (int*)alloc((size_t)NT * 2 * 4);
    int*   slotof = (int*)alloc((size_t)NT * 2 * 4);
    unsigned short* mid = (unsigned short*)alloc((size_t)NT * 2 * HH * 2);
    // ybuf [NT*2][DD] bf16 (16.7 MB) aliases hb+w1t (16.7 MB), both dead before ffn2 runs
    unsigned short* ybuf = (unsigned short*)ws;

    k_prep<<<dim3(2048 + NT / 8), 512, 0, stream>>>(w1, w1t, w2, w2t, h, wg, sel, gv, hb);
    k_scan<<<1, 1024, 0, stream>>>(sel, ctl, rtok, slotof, tiles);
    k_ffn1<<<dim3(FFN1_GRID), 512, 0, stream>>>(hb, w1t, b1, ctl, tiles, rtok, mid);
    k_ffn2<<<dim3(FFN2_GRID), 512, 0, stream>>>(mid, w2t, b2, ctl, tiles, gv, rtok, ybuf);
    k_combine<<<dim3(NT / 4), 512, 0, stream>>>(ybuf, slotof, out);
}